// Round 12
// baseline (133.679 us; speedup 1.0000x reference)
//
#include <hip/hip_runtime.h>
#include <math.h>

typedef __bf16 bf16x8 __attribute__((ext_vector_type(8)));
typedef __bf16 bf16x4 __attribute__((ext_vector_type(4)));
typedef __bf16 bf16x2 __attribute__((ext_vector_type(2)));
typedef float f32x4 __attribute__((ext_vector_type(4)));

namespace {
constexpr int kB = 128, kS = 256, kD = 128, kH = 4;
constexpr float kEps = 1e-6f;
constexpr float kScale = 0.17677669529663687f;  // 1/sqrt(32)
constexpr float kNeg = -1000000000.0f;
constexpr float kLog2e = 1.4426950408889634f;
constexpr size_t kSZ = (size_t)kB * kS * kD;    // 4,194,304
}

// ---------------------------------------------------------------------------
// global->LDS async DMA, 16 B/lane (dest = wave-uniform base + lane*16).
// ---------------------------------------------------------------------------
__device__ __forceinline__ void glds16(const void* g, void* l) {
    __builtin_amdgcn_global_load_lds(
        (const __attribute__((address_space(1))) unsigned int*)g,
        (__attribute__((address_space(3))) unsigned int*)l, 16, 0, 0);
}

// ---------------------------------------------------------------------------
// Weight transpose + convert + PRE-SWIZZLE:
// Wt[m][n*128 + ((k/8)^(n&7))*8 + k%8] = (bf16) W[m][k][n]
// ---------------------------------------------------------------------------
__global__ __launch_bounds__(256) void wtrans(
    const float* __restrict__ Wq, const float* __restrict__ Wk,
    const float* __restrict__ Wv, const float* __restrict__ Wo,
    __bf16* __restrict__ Wt)
{
    const int mtx = blockIdx.x & 3, l = blockIdx.x >> 2;
    const float* W = (mtx == 0 ? Wq : mtx == 1 ? Wk : mtx == 2 ? Wv : Wo) +
                     (size_t)l * kD * kD;
    __bf16* o = Wt + (size_t)blockIdx.x * kD * kD;
    for (int idx = threadIdx.x; idx < kD * kD; idx += 256) {
        const int k = idx >> 7, n = idx & 127;
        o[n * 128 + (((k >> 3) ^ (n & 7)) << 3) + (k & 7)] = (__bf16)W[idx];
    }
}

// ---------------------------------------------------------------------------
// Fused QKV GEMM, 64KB LDS, async W ping-pong (round-11 structure).
// OPERAND-SWAPPED MFMA: acc = mfma(Wfrag, xfrag) -> C col = token, row = n
// (lane holds token m = w*16+lo, n = ni*16+4g+{0..3}) => bf16x4 stores,
// f32x4 bias loads. 4x fewer store instructions than scalar C-layout.
// ---------------------------------------------------------------------------
template <bool F32A>
__global__ __launch_bounds__(512, 4) void qkv_gemm(
    const void* __restrict__ Av, const __bf16* __restrict__ Wt,
    const float* __restrict__ bq, const float* __restrict__ bk,
    const float* __restrict__ bv, __bf16* __restrict__ Qb,
    __bf16* __restrict__ Kb, __bf16* __restrict__ Vb)
{
    __shared__ __bf16 As[128 * 128];
    __shared__ __bf16 Ws[128 * 128];

    const int t = threadIdx.x;
    const int w = t >> 6, l = t & 63, lo = l & 15, g = l >> 4;
    const size_t m0 = (size_t)blockIdx.x * 128;

    // async: W0 -> Ws
#pragma unroll
    for (int it = 0; it < 4; ++it)
        glds16(Wt + (it * 8 + w) * 512 + l * 8, &Ws[(it * 8 + w) * 512]);

    // manual stage A, swizzled
#pragma unroll
    for (int p = 0; p < 4; ++p) {
        const int ci = p * 512 + t;
        const int row = ci >> 4, c = ci & 15;
        if constexpr (F32A) {
            const float* src = (const float*)Av + (m0 + row) * 128 + c * 8;
            const float4 a0 = *(const float4*)src;
            const float4 a1 = *(const float4*)(src + 4);
            bf16x8 o;
            o[0] = (__bf16)a0.x; o[1] = (__bf16)a0.y; o[2] = (__bf16)a0.z; o[3] = (__bf16)a0.w;
            o[4] = (__bf16)a1.x; o[5] = (__bf16)a1.y; o[6] = (__bf16)a1.z; o[7] = (__bf16)a1.w;
            *(bf16x8*)&As[row * 128 + (c ^ (row & 7)) * 8] = o;
        } else {
            *(bf16x8*)&As[row * 128 + (c ^ (row & 7)) * 8] =
                *(const bf16x8*)((const __bf16*)Av + (m0 + row) * 128 + c * 8);
        }
    }
    __syncthreads();   // A visible, W0 landed

    bf16x8 av[4];
    {
        const int arow = w * 16 + lo;
#pragma unroll
        for (int ks = 0; ks < 4; ++ks)
            av[ks] = *(const bf16x8*)&As[arow * 128 + ((g + 4 * ks) ^ (arow & 7)) * 8];
    }
    __syncthreads();   // As reusable as W buffer

    // async: W1 -> As (overlaps m=0 compute)
#pragma unroll
    for (int it = 0; it < 4; ++it)
        glds16(Wt + 16384 + (it * 8 + w) * 512 + l * 8, &As[(it * 8 + w) * 512]);

    const float* biases[3] = {bq, bk, bv};
    __bf16* outs[3] = {Qb, Kb, Vb};
    const __bf16* wbuf[3] = {Ws, As, Ws};

#pragma unroll
    for (int m = 0; m < 3; ++m) {
        const __bf16* wb = wbuf[m];
        f32x4 acc[8];
#pragma unroll
        for (int ni = 0; ni < 8; ++ni) acc[ni] = f32x4{0.f, 0.f, 0.f, 0.f};
#pragma unroll
        for (int ks = 0; ks < 4; ++ks)
#pragma unroll
            for (int ni = 0; ni < 8; ++ni) {
                const int brow = ni * 16 + lo;
                const bf16x8 bv8 =
                    *(const bf16x8*)&wb[brow * 128 + ((g + 4 * ks) ^ (brow & 7)) * 8];
                // swapped: A=W (rows n), B=x (cols token)
                acc[ni] = __builtin_amdgcn_mfma_f32_16x16x32_bf16(bv8, av[ks], acc[ni], 0, 0, 0);
            }
        // epilogue: token = m0+w*16+lo, n = ni*16+4g+{0..3}
        const size_t mrow = (m0 + w * 16 + lo) * 128;
#pragma unroll
        for (int ni = 0; ni < 8; ++ni) {
            const f32x4 bc = *(const f32x4*)(biases[m] + ni * 16 + 4 * g);
            bf16x4 ov;
#pragma unroll
            for (int r = 0; r < 4; ++r) ov[r] = (__bf16)(acc[ni][r] + bc[r]);
            *(bf16x4*)&outs[m][mrow + ni * 16 + 4 * g] = ov;
        }
        if (m == 0) {
            __syncthreads();  // W1 landed; Ws free
#pragma unroll
            for (int it = 0; it < 4; ++it)
                glds16(Wt + 2 * 16384 + (it * 8 + w) * 512 + l * 8,
                       &Ws[(it * 8 + w) * 512]);
        } else if (m == 1) {
            __syncthreads();  // W2 landed
        }
    }
}

// ---------------------------------------------------------------------------
// FUSED attention + O-projection + residual + LayerNorm1.
// Grid 256 strip-major; 512 threads = 8 waves x 16 queries.
// exp2 softmax (no max-sub), async Wo DMA, T14 K/V prefetch, T5 setprio.
// SWAPPED PV: o = mfma(Vfrag, Pfrag) -> lane holds its OWN q (lo) with
// d = nf*16+4g+{0..3} -> no shfl for 1/ls, bf16x4 ctx writes.
// SWAPPED oproj -> bf16x4 O1 stores, f32x4 bias/gamma/beta/resid loads,
// LN row-reduce = 2 shfl_xor (g-lanes only).
// ---------------------------------------------------------------------------
template <int WEIGHTS, bool RESF32>
__global__ __launch_bounds__(512) void attn_oproj(
    const __bf16* __restrict__ Qb, const __bf16* __restrict__ Kb,
    const __bf16* __restrict__ Vb, const float* __restrict__ mask,
    const __bf16* __restrict__ Wo, const float* __restrict__ bo,
    const void* __restrict__ resid, const float* __restrict__ gamma,
    const float* __restrict__ beta, __bf16* __restrict__ O1,
    float* __restrict__ wout, float* __restrict__ l1out)
{
    __shared__ __bf16 Kls[256 * 32];   // [key][32], 4 chunks/row XOR-swizzled
    __shared__ __bf16 Vt[32][270];     // V^T [d][key]
    __shared__ __bf16 Pl[8][16 * 128]; // per-wave half-P, swizzled chunks
    __shared__ __bf16 Ctx[128 * 128];  // swizzled ctx tile
    __shared__ __bf16 Wos[128 * 128];  // swizzled Wo (async DMA)
    __shared__ float mb[256];

    const int t = threadIdx.x;
    const int w = t >> 6, l = t & 63, lo = l & 15, g = l >> 4;
    const int b = blockIdx.x & 127, strip = blockIdx.x >> 7;  // strip-major
    const size_t bbase = (size_t)b * 256 * 128;
    const int q0 = strip * 128 + w * 16;
    const int kswz = (lo ^ (lo >> 2)) & 3;

    // async: Wo -> Wos
#pragma unroll
    for (int it = 0; it < 4; ++it)
        glds16(Wo + (it * 8 + w) * 512 + l * 8, &Wos[(it * 8 + w) * 512]);

    // T14 K/V prefetch registers
    bf16x8 kpre[2], vpre[2];
    const int krow = t >> 2, kc = t & 3;
    const int vkey = t >> 2, vd0 = (t & 3) << 3;

    auto loadKV = [&](int h) {
#pragma unroll
        for (int p = 0; p < 2; ++p)
            kpre[p] = *(const bf16x8*)(Kb + bbase + (size_t)(p * 128 + krow) * 128 +
                                       h * 32 + kc * 8);
#pragma unroll
        for (int p = 0; p < 2; ++p)
            vpre[p] = *(const bf16x8*)(Vb + bbase + (size_t)(p * 128 + vkey) * 128 +
                                       h * 32 + vd0);
    };
    auto writeKV = [&]() {
#pragma unroll
        for (int p = 0; p < 2; ++p) {
            const int row = p * 128 + krow;
            const int sw = (kc ^ ((row ^ (row >> 2)) & 3)) << 3;
            *(bf16x8*)&Kls[row * 32 + sw] = kpre[p];
        }
#pragma unroll
        for (int p = 0; p < 2; ++p) {
            const int key = p * 128 + vkey;
#pragma unroll
            for (int i = 0; i < 8; ++i) Vt[vd0 + i][key] = vpre[p][i];
        }
    };

    if (t < 256) mb[t] = mask[b * 256 + t] * (kNeg * kLog2e);
    if (WEIGHTS && blockIdx.x == 0 && t == 0) l1out[0] = 1024.0f;

    bf16x8 qfr[4];
#pragma unroll
    for (int h = 0; h < 4; ++h)
        qfr[h] = *(const bf16x8*)(Qb + bbase + (size_t)(q0 + lo) * 128 + h * 32 + g * 8);

    loadKV(0);
    writeKV();
    __syncthreads();

#pragma unroll
    for (int h = 0; h < 4; ++h) {
        // S^T = K @ Q^T: lane holds q=lo, keys 16f+4g+r
        f32x4 s[16];
        __builtin_amdgcn_s_setprio(1);
#pragma unroll
        for (int f = 0; f < 16; ++f) {
            const bf16x8 kf =
                *(const bf16x8*)&Kls[(f * 16 + lo) * 32 + ((g ^ kswz) << 3)];
            s[f] = __builtin_amdgcn_mfma_f32_16x16x32_bf16(
                kf, qfr[h], f32x4{0.f, 0.f, 0.f, 0.f}, 0, 0, 0);
        }
        __builtin_amdgcn_s_setprio(0);

        if (h < 3) loadKV(h + 1);

        float ls = 0.f;
#pragma unroll
        for (int f = 0; f < 16; ++f) {
            const f32x4 mk = *(const f32x4*)&mb[f * 16 + g * 4];
#pragma unroll
            for (int r = 0; r < 4; ++r) {
                const float p = __builtin_amdgcn_exp2f(
                    s[f][r] * (kScale * kLog2e) + mk[r]);
                s[f][r] = p;
                ls += p;
            }
        }
        ls += __shfl_xor(ls, 16, 64);
        ls += __shfl_xor(ls, 32, 64);

        if constexpr (WEIGHTS) {
            if (strip == 1 && w == 7 && lo == 15) {
                const float inv = 1.f / ls;
                float* wrow = wout + ((size_t)b * 4 + h) * 256;
#pragma unroll
                for (int f = 0; f < 16; ++f)
#pragma unroll
                    for (int r = 0; r < 4; ++r)
                        wrow[f * 16 + g * 4 + r] = s[f][r] * inv;
            }
        }

        // PV in two half-P passes; swapped operands: o = O[q=lo][d]
        f32x4 o[2] = {f32x4{0.f, 0.f, 0.f, 0.f}, f32x4{0.f, 0.f, 0.f, 0.f}};
#pragma unroll
        for (int half = 0; half < 2; ++half) {
#pragma unroll
            for (int f = 0; f < 8; ++f) {
                const int ff = half * 8 + f;
#pragma unroll
                for (int pr = 0; pr < 2; ++pr) {
                    bf16x2 pk;
                    pk[0] = (__bf16)s[ff][2 * pr];
                    pk[1] = (__bf16)s[ff][2 * pr + 1];
                    const int e = f * 16 + 4 * g + 2 * pr;
                    const int addr =
                        lo * 128 + ((((e >> 3) ^ (lo & 7)) << 3) | (e & 7));
                    *(bf16x2*)&Pl[w][addr] = pk;
                }
            }
            __builtin_amdgcn_s_setprio(1);
#pragma unroll
            for (int ks = 0; ks < 4; ++ks) {
                const int cc = ks * 4 + g;
                const bf16x8 pa =
                    *(const bf16x8*)&Pl[w][lo * 128 + ((cc ^ (lo & 7)) << 3)];
#pragma unroll
                for (int nf = 0; nf < 2; ++nf) {
                    const bf16x8 bv =
                        *(const bf16x8*)&Vt[nf * 16 + lo][(half * 4 + ks) * 32 + g * 8];
                    // swapped: A=V^T (rows d), B=P (cols q)
                    o[nf] = __builtin_amdgcn_mfma_f32_16x16x32_bf16(bv, pa, o[nf], 0, 0, 0);
                }
            }
            __builtin_amdgcn_s_setprio(0);
        }

        // normalized ctx -> swizzled LDS: lane's own q, 4 consecutive d
        {
            const float inv = 1.f / ls;
            const int crow = w * 16 + lo;
#pragma unroll
            for (int nf = 0; nf < 2; ++nf) {
                bf16x4 cv;
#pragma unroll
                for (int r = 0; r < 4; ++r) cv[r] = (__bf16)(o[nf][r] * inv);
                const int col = h * 32 + nf * 16 + 4 * g;
                const int chunk = (col >> 3) ^ (crow & 7);
                *(bf16x4*)&Ctx[crow * 128 + (chunk << 3) + (col & 7)] = cv;
            }
        }
        if (h < 3) {
            __syncthreads();   // all Kls/Vt reads of head h complete
            writeKV();
            __syncthreads();
        }
        // (no barrier after h==3: oproj reads only this wave's Ctx rows)
    }

    // ---- O-projection + residual + LN1 (swapped; lane = one token row) ----
    f32x4 acc[8];
#pragma unroll
    for (int ni = 0; ni < 8; ++ni) acc[ni] = f32x4{0.f, 0.f, 0.f, 0.f};

    const int arow = w * 16 + lo;
#pragma unroll
    for (int ks = 0; ks < 4; ++ks) {
        const bf16x8 av =
            *(const bf16x8*)&Ctx[arow * 128 + (((g + 4 * ks) ^ (arow & 7)) << 3)];
#pragma unroll
        for (int ni = 0; ni < 8; ++ni) {
            const int brow = ni * 16 + lo;
            const bf16x8 bv8 =
                *(const bf16x8*)&Wos[brow * 128 + (((g + 4 * ks) ^ (brow & 7)) << 3)];
            acc[ni] = __builtin_amdgcn_mfma_f32_16x16x32_bf16(bv8, av, acc[ni], 0, 0, 0);
        }
    }

    const size_t mm = (size_t)b * 256 + strip * 128 + w * 16 + lo;  // token row
    f32x4 vv[8];
    float s = 0.f, s2 = 0.f;
#pragma unroll
    for (int ni = 0; ni < 8; ++ni) {
        const f32x4 bc = *(const f32x4*)(bo + ni * 16 + 4 * g);
        f32x4 rv;
        if constexpr (RESF32) {
            rv = *(const f32x4*)((const float*)resid + mm * 128 + ni * 16 + 4 * g);
        } else {
            const bf16x4 rb =
                *(const bf16x4*)((const __bf16*)resid + mm * 128 + ni * 16 + 4 * g);
#pragma unroll
            for (int r = 0; r < 4; ++r) rv[r] = (float)rb[r];
        }
#pragma unroll
        for (int r = 0; r < 4; ++r) {
            const float x = acc[ni][r] + bc[r] + rv[r];
            vv[ni][r] = x;
            s += x;
            s2 += x * x;
        }
    }
    s += __shfl_xor(s, 16, 64);
    s += __shfl_xor(s, 32, 64);
    s2 += __shfl_xor(s2, 16, 64);
    s2 += __shfl_xor(s2, 32, 64);

    const float mu = s * (1.f / 128.f);
    const float var = s2 * (1.f / 128.f) - mu * mu;
    const float rs = rsqrtf(var + kEps);
#pragma unroll
    for (int ni = 0; ni < 8; ++ni) {
        const f32x4 ga = *(const f32x4*)(gamma + ni * 16 + 4 * g);
        const f32x4 be = *(const f32x4*)(beta + ni * 16 + 4 * g);
        bf16x4 ov;
#pragma unroll
        for (int r = 0; r < 4; ++r)
            ov[r] = (__bf16)(ga[r] * (vv[ni][r] - mu) * rs + be[r]);
        *(bf16x4*)&O1[mm * 128 + ni * 16 + 4 * g] = ov;
    }
}

// ---------------------------------------------------------------------------
// FUSED tree aggregation + residual + LayerNorm2 (round-7 known-good).
// ---------------------------------------------------------------------------
__global__ __launch_bounds__(1024) void tree_ln(
    const __bf16* __restrict__ o1, const float* __restrict__ gamma,
    const float* __restrict__ beta, float* __restrict__ xo,
    __bf16* __restrict__ xb, int wf32, int wbf16)
{
    __shared__ float e[255 * 132];
    const int b = blockIdx.x;
    const int t = threadIdx.x;
    const __bf16* ob = o1 + (size_t)b * 256 * 128;

#pragma unroll
    for (int p = 0; p < 4; ++p) {
        const int ci = p * 1024 + t;
        if (ci < 4080) {
            const int row = ci >> 4, c8 = (ci & 15) * 8;
            const bf16x8 v = *(const bf16x8*)(ob + ci * 8);
            float* dst = &e[row * 132 + c8];
#pragma unroll
            for (int i = 0; i < 8; ++i) dst[i] = (float)v[i];
        }
    }
    __syncthreads();

    {
        const int wv = t >> 6, ln = t & 63;
        const int col = wv * 8 + (ln & 7);
        const int nsub = ln >> 3;
        for (int lvl = 6; lvl >= 0; --lvl) {
            const int p0 = (1 << lvl) - 1;
            const int cnt = 1 << lvl;
            for (int base = 0; base < cnt; base += 8) {
                const int p = p0 + base + nsub;
                if (base + nsub < cnt) {
                    e[p * 132 + col] =
                        tanhf(e[(2 * p + 1) * 132 + col] + e[(2 * p + 2) * 132 + col]);
                }
            }
        }
    }
    __syncthreads();

    const int wv = t >> 6, lane = t & 63;
    const float2 gv = *(const float2*)(gamma + lane * 2);
    const float2 bb = *(const float2*)(beta + lane * 2);
    for (int row = wv; row < 256; row += 16) {
        const int c = lane * 2;
        float y0, y1;
        if (row >= 127 && row < 255) {
            y0 = 2.f * e[row * 132 + c];
            y1 = 2.f * e[row * 132 + c + 1];
        } else if (row < 127) {
            const bf16x2 v = *(const bf16x2*)(ob + (size_t)row * 128 + c);
            y0 = (float)v[0] + e[row * 132 + c];
            y1 = (float)v[1] + e[row * 132 + c + 1];
        } else {
            const bf16x2 v = *(const bf16x2*)(ob + (size_t)row * 128 + c);
            y0 = 2.f * (float)v[0];
            y1 = 2.f * (float)v[1];
        }
        float s = y0 + y1, s2 = y0 * y0 + y1 * y1;
#pragma unroll
        for (int o = 1; o < 64; o <<= 1) {
            s += __shfl_xor(s, o, 64);
            s2 += __shfl_xor(s2, o, 64);
        }
        const float mu = s * (1.f / 128.f);
        const float var = s2 * (1.f / 128.f) - mu * mu;
        const float rs = rsqrtf(var + kEps);
        const float r0 = gv.x * (y0 - mu) * rs + bb.x;
        const float r1 = gv.y * (y1 - mu) * rs + bb.y;
        const size_t off = ((size_t)b * 256 + row) * 128 + c;
        if (wf32) {
            float2 o2; o2.x = r0; o2.y = r1;
            *(float2*)(xo + off) = o2;
        }
        if (wbf16) {
            bf16x2 ob2; ob2[0] = (__bf16)r0; ob2[1] = (__bf16)r1;
            *(bf16x2*)(xb + off) = ob2;
        }
    }
}

// ---------------------------------------------------------------------------
extern "C" void kernel_launch(void* const* d_in, const int* in_sizes, int n_in,
                              void* d_out, int out_size, void* d_ws, size_t ws_size,
                              hipStream_t stream)
{
    (void)in_sizes; (void)n_in; (void)out_size; (void)ws_size;

    const float* x_in = (const float*)d_in[0];
    const float* mask = (const float*)d_in[1];
    const float* Wq = (const float*)d_in[5];
    const float* bq = (const float*)d_in[6];
    const float* Wk = (const float*)d_in[7];
    const float* bk = (const float*)d_in[8];
    const float* Wv = (const float*)d_in[9];
    const float* bv = (const float*)d_in[10];
    const float* Wo = (const float*)d_in[11];
    const float* bo = (const float*)d_in[12];
    const float* g1 = (const float*)d_in[13];
    const float* b1 = (const float*)d_in[14];
    const float* g2 = (const float*)d_in[15];
    const float* b2 = (const float*)d_in[16];

    float* out_x = (float*)d_out;
    float* out_l1 = out_x + kSZ;
    float* out_w = out_l1 + 1;

    char* wsb = (char*)d_ws;
    __bf16* Qb = (__bf16*)wsb;
    __bf16* Kb = (__bf16*)(wsb + 1 * kSZ * 2);
    __bf16* Vb = (__bf16*)(wsb + 2 * kSZ * 2);
    __bf16* O1 = (__bf16*)(wsb + 3 * kSZ * 2);
    __bf16* xb = (__bf16*)(wsb + 4 * kSZ * 2);
    __bf16* Wt = (__bf16*)(wsb + 5 * kSZ * 2);   // 8 * 16384 bf16, pre-swizzled

    wtrans<<<8, 256, 0, stream>>>(Wq, Wk, Wv, Wo, Wt);

    // ---- layer 0 (f32 x_in) ----
    qkv_gemm<true><<<256, 512, 0, stream>>>(x_in, Wt, bq, bk, bv, Qb, Kb, Vb);
    attn_oproj<0, true><<<256, 512, 0, stream>>>(Qb, Kb, Vb, mask,
                                                 Wt + 3 * kD * kD, bo,
                                                 x_in, g1, b1, O1,
                                                 nullptr, nullptr);
    tree_ln<<<128, 1024, 0, stream>>>(O1, g2, b2, nullptr, xb, 0, 1);

    // ---- layer 1 (bf16 xb) ----
    const __bf16* WtL = Wt + 4 * kD * kD;
    qkv_gemm<false><<<256, 512, 0, stream>>>(xb, WtL, bq + kD, bk + kD, bv + kD,
                                             Qb, Kb, Vb);
    attn_oproj<1, false><<<256, 512, 0, stream>>>(Qb, Kb, Vb, mask,
                                                  WtL + 3 * kD * kD, bo + kD,
                                                  xb, g1 + kD, b1 + kD, O1,
                                                  out_w, out_l1);
    tree_ln<<<128, 1024, 0, stream>>>(O1, g2 + kD, b2 + kD, out_x, nullptr, 1, 0);
}

// Round 13
// 124.262 us; speedup vs baseline: 1.0758x; 1.0758x over previous
//
#include <hip/hip_runtime.h>
#include <math.h>

typedef __bf16 bf16x8 __attribute__((ext_vector_type(8)));
typedef __bf16 bf16x2 __attribute__((ext_vector_type(2)));
typedef float f32x4 __attribute__((ext_vector_type(4)));

namespace {
constexpr int kB = 128, kS = 256, kD = 128, kH = 4;
constexpr float kEps = 1e-6f;
constexpr float kScale = 0.17677669529663687f;  // 1/sqrt(32)
constexpr float kNeg = -1000000000.0f;
constexpr float kLog2e = 1.4426950408889634f;
constexpr size_t kSZ = (size_t)kB * kS * kD;    // 4,194,304
}

// ---------------------------------------------------------------------------
// global->LDS async DMA, 16 B/lane (dest = wave-uniform base + lane*16).
// ---------------------------------------------------------------------------
__device__ __forceinline__ void glds16(const void* g, void* l) {
    __builtin_amdgcn_global_load_lds(
        (const __attribute__((address_space(1))) unsigned int*)g,
        (__attribute__((address_space(3))) unsigned int*)l, 16, 0, 0);
}

// ---------------------------------------------------------------------------
// Weight transpose + convert + PRE-SWIZZLE:
// Wt[m][n*128 + ((k/8)^(n&7))*8 + k%8] = (bf16) W[m][k][n]
// ---------------------------------------------------------------------------
__global__ __launch_bounds__(256) void wtrans(
    const float* __restrict__ Wq, const float* __restrict__ Wk,
    const float* __restrict__ Wv, const float* __restrict__ Wo,
    __bf16* __restrict__ Wt)
{
    const int mtx = blockIdx.x & 3, l = blockIdx.x >> 2;
    const float* W = (mtx == 0 ? Wq : mtx == 1 ? Wk : mtx == 2 ? Wv : Wo) +
                     (size_t)l * kD * kD;
    __bf16* o = Wt + (size_t)blockIdx.x * kD * kD;
    for (int idx = threadIdx.x; idx < kD * kD; idx += 256) {
        const int k = idx >> 7, n = idx & 127;
        o[n * 128 + (((k >> 3) ^ (n & 7)) << 3) + (k & 7)] = (__bf16)W[idx];
    }
}

// ---------------------------------------------------------------------------
// Fused QKV GEMM (round-11 known-good body), 64KB LDS, async W ping-pong.
// STRIP-MAJOR tile numbering: bid -> tile (bid&127)*2 + (bid>>7), so the two
// tiles of batch b are produced by blocks b and 128+b -> both on XCD b%8,
// matching the attn consumer blocks -> Q/K/V reads are L2 hits (T1).
// ---------------------------------------------------------------------------
template <bool F32A>
__global__ __launch_bounds__(512, 4) void qkv_gemm(
    const void* __restrict__ Av, const __bf16* __restrict__ Wt,
    const float* __restrict__ bq, const float* __restrict__ bk,
    const float* __restrict__ bv, __bf16* __restrict__ Qb,
    __bf16* __restrict__ Kb, __bf16* __restrict__ Vb)
{
    __shared__ __bf16 As[128 * 128];
    __shared__ __bf16 Ws[128 * 128];

    const int t = threadIdx.x;
    const int w = t >> 6, l = t & 63, lo = l & 15, g = l >> 4;
    const int tile = ((blockIdx.x & 127) << 1) | (blockIdx.x >> 7);
    const size_t m0 = (size_t)tile * 128;

    // async: W0 -> Ws
#pragma unroll
    for (int it = 0; it < 4; ++it)
        glds16(Wt + (it * 8 + w) * 512 + l * 8, &Ws[(it * 8 + w) * 512]);

    // manual stage A, swizzled
#pragma unroll
    for (int p = 0; p < 4; ++p) {
        const int ci = p * 512 + t;
        const int row = ci >> 4, c = ci & 15;
        if constexpr (F32A) {
            const float* src = (const float*)Av + (m0 + row) * 128 + c * 8;
            const float4 a0 = *(const float4*)src;
            const float4 a1 = *(const float4*)(src + 4);
            bf16x8 o;
            o[0] = (__bf16)a0.x; o[1] = (__bf16)a0.y; o[2] = (__bf16)a0.z; o[3] = (__bf16)a0.w;
            o[4] = (__bf16)a1.x; o[5] = (__bf16)a1.y; o[6] = (__bf16)a1.z; o[7] = (__bf16)a1.w;
            *(bf16x8*)&As[row * 128 + (c ^ (row & 7)) * 8] = o;
        } else {
            *(bf16x8*)&As[row * 128 + (c ^ (row & 7)) * 8] =
                *(const bf16x8*)((const __bf16*)Av + (m0 + row) * 128 + c * 8);
        }
    }
    __syncthreads();   // A visible, W0 landed

    bf16x8 av[4];
    {
        const int arow = w * 16 + lo;
#pragma unroll
        for (int ks = 0; ks < 4; ++ks)
            av[ks] = *(const bf16x8*)&As[arow * 128 + ((g + 4 * ks) ^ (arow & 7)) * 8];
    }
    __syncthreads();   // As reusable as W buffer

    // async: W1 -> As (overlaps m=0 compute)
#pragma unroll
    for (int it = 0; it < 4; ++it)
        glds16(Wt + 16384 + (it * 8 + w) * 512 + l * 8, &As[(it * 8 + w) * 512]);

    const float* biases[3] = {bq, bk, bv};
    __bf16* outs[3] = {Qb, Kb, Vb};
    const __bf16* wbuf[3] = {Ws, As, Ws};

#pragma unroll
    for (int m = 0; m < 3; ++m) {
        const __bf16* wb = wbuf[m];
        f32x4 acc[8];
#pragma unroll
        for (int ni = 0; ni < 8; ++ni) acc[ni] = f32x4{0.f, 0.f, 0.f, 0.f};
#pragma unroll
        for (int ks = 0; ks < 4; ++ks)
#pragma unroll
            for (int ni = 0; ni < 8; ++ni) {
                const int brow = ni * 16 + lo;
                const bf16x8 bv8 =
                    *(const bf16x8*)&wb[brow * 128 + ((g + 4 * ks) ^ (brow & 7)) * 8];
                acc[ni] = __builtin_amdgcn_mfma_f32_16x16x32_bf16(av[ks], bv8, acc[ni], 0, 0, 0);
            }
#pragma unroll
        for (int ni = 0; ni < 8; ++ni) {
            const float bc = biases[m][ni * 16 + lo];
#pragma unroll
            for (int r = 0; r < 4; ++r)
                outs[m][(m0 + w * 16 + g * 4 + r) * 128 + ni * 16 + lo] =
                    (__bf16)(acc[ni][r] + bc);
        }
        if (m == 0) {
            __syncthreads();  // W1 landed; Ws free
#pragma unroll
            for (int it = 0; it < 4; ++it)
                glds16(Wt + 2 * 16384 + (it * 8 + w) * 512 + l * 8,
                       &Ws[(it * 8 + w) * 512]);
        } else if (m == 1) {
            __syncthreads();  // W2 landed
        }
    }
}

// ---------------------------------------------------------------------------
// FUSED attention + O-projection + residual + LayerNorm1.
// Grid 256 strip-major; 512 threads = 8 waves x 16 queries.
// exp2 softmax (no max-sub), async Wo DMA, T14 K/V prefetch, T5 setprio.
// NEW: DOUBLE-BUFFERED Kls/Vt -> writeKV targets the idle buffer, issued
// right after softmax (hidden under PV); ONE barrier per head instead of 2.
// Pl shrunk to quarter-passes (16x64/wave) to fit LDS (147.6 KB total).
// WEIGHTS: wave holding q=255 emits softmax rows; total_l1 = 1024 exactly.
// ---------------------------------------------------------------------------
template <int WEIGHTS, bool RESF32>
__global__ __launch_bounds__(512) void attn_oproj(
    const __bf16* __restrict__ Qb, const __bf16* __restrict__ Kb,
    const __bf16* __restrict__ Vb, const float* __restrict__ mask,
    const __bf16* __restrict__ Wo, const float* __restrict__ bo,
    const void* __restrict__ resid, const float* __restrict__ gamma,
    const float* __restrict__ beta, __bf16* __restrict__ O1,
    float* __restrict__ wout, float* __restrict__ l1out)
{
    __shared__ __bf16 Kls[2][256 * 32];  // double-buffered, XOR-swizzled
    __shared__ __bf16 Vt[2][32][270];    // double-buffered V^T [d][key]
    __shared__ __bf16 Pl[8][16 * 64];    // per-wave quarter-P, swizzled
    __shared__ __bf16 Ctx[128 * 128];    // swizzled ctx tile
    __shared__ __bf16 Wos[128 * 128];    // swizzled Wo (async DMA)
    __shared__ float mb[256];

    const int t = threadIdx.x;
    const int w = t >> 6, l = t & 63, lo = l & 15, g = l >> 4;
    const int b = blockIdx.x & 127, strip = blockIdx.x >> 7;  // strip-major
    const size_t bbase = (size_t)b * 256 * 128;
    const int q0 = strip * 128 + w * 16;
    const int kswz = (lo ^ (lo >> 2)) & 3;

    // async: Wo -> Wos (consumed after the head loop)
#pragma unroll
    for (int it = 0; it < 4; ++it)
        glds16(Wo + (it * 8 + w) * 512 + l * 8, &Wos[(it * 8 + w) * 512]);

    // T14 K/V prefetch registers
    bf16x8 kpre[2], vpre[2];
    const int krow = t >> 2, kc = t & 3;
    const int vkey = t >> 2, vd0 = (t & 3) << 3;

    auto loadKV = [&](int h) {
#pragma unroll
        for (int p = 0; p < 2; ++p)
            kpre[p] = *(const bf16x8*)(Kb + bbase + (size_t)(p * 128 + krow) * 128 +
                                       h * 32 + kc * 8);
#pragma unroll
        for (int p = 0; p < 2; ++p)
            vpre[p] = *(const bf16x8*)(Vb + bbase + (size_t)(p * 128 + vkey) * 128 +
                                       h * 32 + vd0);
    };
    auto writeKV = [&](int buf) {
#pragma unroll
        for (int p = 0; p < 2; ++p) {
            const int row = p * 128 + krow;
            const int sw = (kc ^ ((row ^ (row >> 2)) & 3)) << 3;
            *(bf16x8*)&Kls[buf][row * 32 + sw] = kpre[p];
        }
#pragma unroll
        for (int p = 0; p < 2; ++p) {
            const int key = p * 128 + vkey;
#pragma unroll
            for (int i = 0; i < 8; ++i) Vt[buf][vd0 + i][key] = vpre[p][i];
        }
    };

    if (t < 256) mb[t] = mask[b * 256 + t] * (kNeg * kLog2e);
    if (WEIGHTS && blockIdx.x == 0 && t == 0) l1out[0] = 1024.0f;

    bf16x8 qfr[4];
#pragma unroll
    for (int h = 0; h < 4; ++h)
        qfr[h] = *(const bf16x8*)(Qb + bbase + (size_t)(q0 + lo) * 128 + h * 32 + g * 8);

    loadKV(0);
    writeKV(0);
    __syncthreads();

#pragma unroll
    for (int h = 0; h < 4; ++h) {
        const int cur = h & 1;
        // S^T = K @ Q^T: lane holds q=lo, keys 16f+4g+r
        f32x4 s[16];
        __builtin_amdgcn_s_setprio(1);
#pragma unroll
        for (int f = 0; f < 16; ++f) {
            const bf16x8 kf =
                *(const bf16x8*)&Kls[cur][(f * 16 + lo) * 32 + ((g ^ kswz) << 3)];
            s[f] = __builtin_amdgcn_mfma_f32_16x16x32_bf16(
                kf, qfr[h], f32x4{0.f, 0.f, 0.f, 0.f}, 0, 0, 0);
        }
        __builtin_amdgcn_s_setprio(0);

        if (h < 3) loadKV(h + 1);  // T14: issue next head's K/V now

        float ls = 0.f;
#pragma unroll
        for (int f = 0; f < 16; ++f) {
            const f32x4 mk = *(const f32x4*)&mb[f * 16 + g * 4];
#pragma unroll
            for (int r = 0; r < 4; ++r) {
                const float p = __builtin_amdgcn_exp2f(
                    s[f][r] * (kScale * kLog2e) + mk[r]);
                s[f][r] = p;
                ls += p;
            }
        }
        ls += __shfl_xor(ls, 16, 64);
        ls += __shfl_xor(ls, 32, 64);

        if constexpr (WEIGHTS) {
            if (strip == 1 && w == 7 && lo == 15) {
                const float inv = 1.f / ls;
                float* wrow = wout + ((size_t)b * 4 + h) * 256;
#pragma unroll
                for (int f = 0; f < 16; ++f)
#pragma unroll
                    for (int r = 0; r < 4; ++r)
                        wrow[f * 16 + g * 4 + r] = s[f][r] * inv;
            }
        }

        // stage next head's K/V into the IDLE buffer (no reader conflict;
        // store latency hides under the PV passes below)
        if (h < 3) writeKV(cur ^ 1);

        // PV in four quarter-P passes (64 keys each)
        f32x4 o[2] = {f32x4{0.f, 0.f, 0.f, 0.f}, f32x4{0.f, 0.f, 0.f, 0.f}};
#pragma unroll
        for (int qt = 0; qt < 4; ++qt) {
#pragma unroll
            for (int fl = 0; fl < 4; ++fl) {
                const int ff = qt * 4 + fl;
#pragma unroll
                for (int pr = 0; pr < 2; ++pr) {
                    bf16x2 pk;
                    pk[0] = (__bf16)s[ff][2 * pr];
                    pk[1] = (__bf16)s[ff][2 * pr + 1];
                    const int e = fl * 16 + 4 * g + 2 * pr;  // 0..63
                    const int addr =
                        lo * 64 + ((((e >> 3) ^ (lo & 7)) << 3) | (e & 7));
                    *(bf16x2*)&Pl[w][addr] = pk;
                }
            }
            __builtin_amdgcn_s_setprio(1);
#pragma unroll
            for (int ksl = 0; ksl < 2; ++ksl) {
                const int cc = ksl * 4 + g;
                const bf16x8 pa =
                    *(const bf16x8*)&Pl[w][lo * 64 + ((cc ^ (lo & 7)) << 3)];
#pragma unroll
                for (int nf = 0; nf < 2; ++nf) {
                    const bf16x8 bv =
                        *(const bf16x8*)&Vt[cur][nf * 16 + lo][(qt * 2 + ksl) * 32 + g * 8];
                    o[nf] = __builtin_amdgcn_mfma_f32_16x16x32_bf16(pa, bv, o[nf], 0, 0, 0);
                }
            }
            __builtin_amdgcn_s_setprio(0);
        }

        // normalized ctx -> swizzled LDS tile (cols h*32..h*32+31)
#pragma unroll
        for (int r = 0; r < 4; ++r) {
            const float inv = 1.f / __shfl(ls, 4 * g + r, 64);
            const int crow = w * 16 + g * 4 + r;
#pragma unroll
            for (int nf = 0; nf < 2; ++nf) {
                const int col = h * 32 + nf * 16 + lo;
                const int chunk = (col >> 3) ^ (crow & 7);
                Ctx[crow * 128 + (chunk << 3) + (col & 7)] = (__bf16)(o[nf][r] * inv);
            }
        }
        if (h < 3) __syncthreads();  // next buffer fully staged, block-wide
        // (no barrier after h==3: oproj reads only this wave's Ctx rows)
    }

    // ---- O-projection + residual + LN1 (wave = 16 rows) ----
    const size_t m0 = (size_t)b * 256 + strip * 128;
    f32x4 acc[8];
#pragma unroll
    for (int ni = 0; ni < 8; ++ni) acc[ni] = f32x4{0.f, 0.f, 0.f, 0.f};

    const int arow = w * 16 + lo;
#pragma unroll
    for (int ks = 0; ks < 4; ++ks) {
        const bf16x8 av =
            *(const bf16x8*)&Ctx[arow * 128 + (((g + 4 * ks) ^ (arow & 7)) << 3)];
#pragma unroll
        for (int ni = 0; ni < 8; ++ni) {
            const int brow = ni * 16 + lo;
            const bf16x8 bv8 =
                *(const bf16x8*)&Wos[brow * 128 + (((g + 4 * ks) ^ (brow & 7)) << 3)];
            acc[ni] = __builtin_amdgcn_mfma_f32_16x16x32_bf16(av, bv8, acc[ni], 0, 0, 0);
        }
    }

    float bcol[8], ga[8], be[8];
#pragma unroll
    for (int ni = 0; ni < 8; ++ni) {
        bcol[ni] = bo[ni * 16 + lo];
        ga[ni] = gamma[ni * 16 + lo];
        be[ni] = beta[ni * 16 + lo];
    }

    float vv[4][8];
    float s[4] = {0, 0, 0, 0}, s2[4] = {0, 0, 0, 0};
#pragma unroll
    for (int r = 0; r < 4; ++r) {
        const size_t mm = m0 + w * 16 + g * 4 + r;
#pragma unroll
        for (int ni = 0; ni < 8; ++ni) {
            float rv;
            if constexpr (RESF32)
                rv = ((const float*)resid)[mm * 128 + ni * 16 + lo];
            else
                rv = (float)((const __bf16*)resid)[mm * 128 + ni * 16 + lo];
            const float x = acc[ni][r] + bcol[ni] + rv;
            vv[r][ni] = x; s[r] += x; s2[r] += x * x;
        }
    }
#pragma unroll
    for (int r = 0; r < 4; ++r)
#pragma unroll
        for (int o = 1; o < 16; o <<= 1) {
            s[r] += __shfl_xor(s[r], o, 64);
            s2[r] += __shfl_xor(s2[r], o, 64);
        }
#pragma unroll
    for (int r = 0; r < 4; ++r) {
        const float mu = s[r] * (1.f / 128.f);
        const float var = s2[r] * (1.f / 128.f) - mu * mu;
        const float rs = rsqrtf(var + kEps);
        const size_t mm = m0 + w * 16 + g * 4 + r;
#pragma unroll
        for (int ni = 0; ni < 8; ++ni)
            O1[mm * 128 + ni * 16 + lo] =
                (__bf16)(ga[ni] * (vv[r][ni] - mu) * rs + be[ni]);
    }
}

// ---------------------------------------------------------------------------
// FUSED tree aggregation + residual + LayerNorm2 (round-7 known-good).
// ---------------------------------------------------------------------------
__global__ __launch_bounds__(1024) void tree_ln(
    const __bf16* __restrict__ o1, const float* __restrict__ gamma,
    const float* __restrict__ beta, float* __restrict__ xo,
    __bf16* __restrict__ xb, int wf32, int wbf16)
{
    __shared__ float e[255 * 132];
    const int b = blockIdx.x;
    const int t = threadIdx.x;
    const __bf16* ob = o1 + (size_t)b * 256 * 128;

#pragma unroll
    for (int p = 0; p < 4; ++p) {
        const int ci = p * 1024 + t;
        if (ci < 4080) {
            const int row = ci >> 4, c8 = (ci & 15) * 8;
            const bf16x8 v = *(const bf16x8*)(ob + ci * 8);
            float* dst = &e[row * 132 + c8];
#pragma unroll
            for (int i = 0; i < 8; ++i) dst[i] = (float)v[i];
        }
    }
    __syncthreads();

    {
        const int wv = t >> 6, ln = t & 63;
        const int col = wv * 8 + (ln & 7);
        const int nsub = ln >> 3;
        for (int lvl = 6; lvl >= 0; --lvl) {
            const int p0 = (1 << lvl) - 1;
            const int cnt = 1 << lvl;
            for (int base = 0; base < cnt; base += 8) {
                const int p = p0 + base + nsub;
                if (base + nsub < cnt) {
                    e[p * 132 + col] =
                        tanhf(e[(2 * p + 1) * 132 + col] + e[(2 * p + 2) * 132 + col]);
                }
            }
        }
    }
    __syncthreads();

    const int wv = t >> 6, lane = t & 63;
    const float2 gv = *(const float2*)(gamma + lane * 2);
    const float2 bb = *(const float2*)(beta + lane * 2);
    for (int row = wv; row < 256; row += 16) {
        const int c = lane * 2;
        float y0, y1;
        if (row >= 127 && row < 255) {
            y0 = 2.f * e[row * 132 + c];
            y1 = 2.f * e[row * 132 + c + 1];
        } else if (row < 127) {
            const bf16x2 v = *(const bf16x2*)(ob + (size_t)row * 128 + c);
            y0 = (float)v[0] + e[row * 132 + c];
            y1 = (float)v[1] + e[row * 132 + c + 1];
        } else {
            const bf16x2 v = *(const bf16x2*)(ob + (size_t)row * 128 + c);
            y0 = 2.f * (float)v[0];
            y1 = 2.f * (float)v[1];
        }
        float s = y0 + y1, s2 = y0 * y0 + y1 * y1;
#pragma unroll
        for (int o = 1; o < 64; o <<= 1) {
            s += __shfl_xor(s, o, 64);
            s2 += __shfl_xor(s2, o, 64);
        }
        const float mu = s * (1.f / 128.f);
        const float var = s2 * (1.f / 128.f) - mu * mu;
        const float rs = rsqrtf(var + kEps);
        const float r0 = gv.x * (y0 - mu) * rs + bb.x;
        const float r1 = gv.y * (y1 - mu) * rs + bb.y;
        const size_t off = ((size_t)b * 256 + row) * 128 + c;
        if (wf32) {
            float2 o2; o2.x = r0; o2.y = r1;
            *(float2*)(xo + off) = o2;
        }
        if (wbf16) {
            bf16x2 ob2; ob2[0] = (__bf16)r0; ob2[1] = (__bf16)r1;
            *(bf16x2*)(xb + off) = ob2;
        }
    }
}

// ---------------------------------------------------------------------------
extern "C" void kernel_launch(void* const* d_in, const int* in_sizes, int n_in,
                              void* d_out, int out_size, void* d_ws, size_t ws_size,
                              hipStream_t stream)
{
    (void)in_sizes; (void)n_in; (void)out_size; (void)ws_size;

    const float* x_in = (const float*)d_in[0];
    const float* mask = (const float*)d_in[1];
    const float* Wq = (const float*)d_in[5];
    const float* bq = (const float*)d_in[6];
    const float* Wk = (const float*)d_in[7];
    const float* bk = (const float*)d_in[8];
    const float* Wv = (const float*)d_in[9];
    const float* bv = (const float*)d_in[10];
    const float* Wo = (const float*)d_in[11];
    const float* bo = (const float*)d_in[12];
    const float* g1 = (const float*)d_in[13];
    const float* b1 = (const float*)d_in[14];
    const float* g2 = (const float*)d_in[15];
    const float* b2 = (const float*)d_in[16];

    float* out_x = (float*)d_out;
    float* out_l1 = out_x + kSZ;
    float* out_w = out_l1 + 1;

    char* wsb = (char*)d_ws;
    __bf16* Qb = (__bf16*)wsb;
    __bf16* Kb = (__bf16*)(wsb + 1 * kSZ * 2);
    __bf16* Vb = (__bf16*)(wsb + 2 * kSZ * 2);
    __bf16* O1 = (__bf16*)(wsb + 3 * kSZ * 2);
    __bf16* xb = (__bf16*)(wsb + 4 * kSZ * 2);
    __bf16* Wt = (__bf16*)(wsb + 5 * kSZ * 2);   // 8 * 16384 bf16, pre-swizzled

    wtrans<<<8, 256, 0, stream>>>(Wq, Wk, Wv, Wo, Wt);

    // ---- layer 0 (f32 x_in) ----
    qkv_gemm<true><<<256, 512, 0, stream>>>(x_in, Wt, bq, bk, bv, Qb, Kb, Vb);
    attn_oproj<0, true><<<256, 512, 0, stream>>>(Qb, Kb, Vb, mask,
                                                 Wt + 3 * kD * kD, bo,
                                                 x_in, g1, b1, O1,
                                                 nullptr, nullptr);
    tree_ln<<<128, 1024, 0, stream>>>(O1, g2, b2, nullptr, xb, 0, 1);

    // ---- layer 1 (bf16 xb) ----
    const __bf16* WtL = Wt + 4 * kD * kD;
    qkv_gemm<false><<<256, 512, 0, stream>>>(xb, WtL, bq + kD, bk + kD, bv + kD,
                                             Qb, Kb, Vb);
    attn_oproj<1, false><<<256, 512, 0, stream>>>(Qb, Kb, Vb, mask,
                                                  WtL + 3 * kD * kD, bo + kD,
                                                  xb, g1 + kD, b1 + kD, O1,
                                                  out_w, out_l1);
    tree_ln<<<128, 1024, 0, stream>>>(O1, g2 + kD, b2 + kD, out_x, nullptr, 1, 0);
}

// Round 14
// 116.326 us; speedup vs baseline: 1.1492x; 1.0682x over previous
//
#include <hip/hip_runtime.h>
#include <math.h>

typedef __bf16 bf16x8 __attribute__((ext_vector_type(8)));
typedef __bf16 bf16x2 __attribute__((ext_vector_type(2)));
typedef float f32x4 __attribute__((ext_vector_type(4)));

namespace {
constexpr int kB = 128, kS = 256, kD = 128, kH = 4;
constexpr float kEps = 1e-6f;
constexpr float kScale = 0.17677669529663687f;  // 1/sqrt(32)
constexpr float kNeg = -1000000000.0f;
constexpr float kLog2e = 1.4426950408889634f;
constexpr size_t kSZ = (size_t)kB * kS * kD;    // 4,194,304
}

// ---------------------------------------------------------------------------
// global->LDS async DMA, 16 B/lane (dest = wave-uniform base + lane*16).
// ---------------------------------------------------------------------------
__device__ __forceinline__ void glds16(const void* g, void* l) {
    __builtin_amdgcn_global_load_lds(
        (const __attribute__((address_space(1))) unsigned int*)g,
        (__attribute__((address_space(3))) unsigned int*)l, 16, 0, 0);
}

// ---------------------------------------------------------------------------
// Weight transpose + convert + PRE-SWIZZLE:
// Wt[m][n*128 + ((k/8)^(n&7))*8 + k%8] = (bf16) W[m][k][n]
// ---------------------------------------------------------------------------
__global__ __launch_bounds__(256) void wtrans(
    const float* __restrict__ Wq, const float* __restrict__ Wk,
    const float* __restrict__ Wv, const float* __restrict__ Wo,
    __bf16* __restrict__ Wt)
{
    const int mtx = blockIdx.x & 3, l = blockIdx.x >> 2;
    const float* W = (mtx == 0 ? Wq : mtx == 1 ? Wk : mtx == 2 ? Wv : Wo) +
                     (size_t)l * kD * kD;
    __bf16* o = Wt + (size_t)blockIdx.x * kD * kD;
    for (int idx = threadIdx.x; idx < kD * kD; idx += 256) {
        const int k = idx >> 7, n = idx & 127;
        o[n * 128 + (((k >> 3) ^ (n & 7)) << 3) + (k & 7)] = (__bf16)W[idx];
    }
}

// ---------------------------------------------------------------------------
// Fused QKV GEMM, 64KB LDS, async W ping-pong, strip-major tiles (r13).
// NEW: for bf16 input (layer 1), A is stored PRE-SWIZZLED by tree_ln, so the
// A tile is staged via async global_load_lds too (overlaps W0 DMA; no manual
// cvt/ds_write chain at block start).
// ---------------------------------------------------------------------------
template <bool F32A>
__global__ __launch_bounds__(512, 4) void qkv_gemm(
    const void* __restrict__ Av, const __bf16* __restrict__ Wt,
    const float* __restrict__ bq, const float* __restrict__ bk,
    const float* __restrict__ bv, __bf16* __restrict__ Qb,
    __bf16* __restrict__ Kb, __bf16* __restrict__ Vb)
{
    __shared__ __bf16 As[128 * 128];
    __shared__ __bf16 Ws[128 * 128];

    const int t = threadIdx.x;
    const int w = t >> 6, l = t & 63, lo = l & 15, g = l >> 4;
    const int tile = ((blockIdx.x & 127) << 1) | (blockIdx.x >> 7);
    const size_t m0 = (size_t)tile * 128;

    // async: W0 -> Ws
#pragma unroll
    for (int it = 0; it < 4; ++it)
        glds16(Wt + (it * 8 + w) * 512 + l * 8, &Ws[(it * 8 + w) * 512]);

    if constexpr (F32A) {
        // manual stage A (cvt f32->bf16), swizzled
#pragma unroll
        for (int p = 0; p < 4; ++p) {
            const int ci = p * 512 + t;
            const int row = ci >> 4, c = ci & 15;
            const float* src = (const float*)Av + (m0 + row) * 128 + c * 8;
            const float4 a0 = *(const float4*)src;
            const float4 a1 = *(const float4*)(src + 4);
            bf16x8 o;
            o[0] = (__bf16)a0.x; o[1] = (__bf16)a0.y; o[2] = (__bf16)a0.z; o[3] = (__bf16)a0.w;
            o[4] = (__bf16)a1.x; o[5] = (__bf16)a1.y; o[6] = (__bf16)a1.z; o[7] = (__bf16)a1.w;
            *(bf16x8*)&As[row * 128 + (c ^ (row & 7)) * 8] = o;
        }
    } else {
        // A is pre-swizzled bf16 -> linear async DMA
#pragma unroll
        for (int it = 0; it < 4; ++it)
            glds16((const __bf16*)Av + m0 * 128 + (it * 8 + w) * 512 + l * 8,
                   &As[(it * 8 + w) * 512]);
    }
    __syncthreads();   // A visible, W0 landed

    bf16x8 av[4];
    {
        const int arow = w * 16 + lo;
#pragma unroll
        for (int ks = 0; ks < 4; ++ks)
            av[ks] = *(const bf16x8*)&As[arow * 128 + ((g + 4 * ks) ^ (arow & 7)) * 8];
    }
    __syncthreads();   // As reusable as W buffer

    // async: W1 -> As (overlaps m=0 compute)
#pragma unroll
    for (int it = 0; it < 4; ++it)
        glds16(Wt + 16384 + (it * 8 + w) * 512 + l * 8, &As[(it * 8 + w) * 512]);

    const float* biases[3] = {bq, bk, bv};
    __bf16* outs[3] = {Qb, Kb, Vb};
    const __bf16* wbuf[3] = {Ws, As, Ws};

#pragma unroll
    for (int m = 0; m < 3; ++m) {
        const __bf16* wb = wbuf[m];
        f32x4 acc[8];
#pragma unroll
        for (int ni = 0; ni < 8; ++ni) acc[ni] = f32x4{0.f, 0.f, 0.f, 0.f};
#pragma unroll
        for (int ks = 0; ks < 4; ++ks)
#pragma unroll
            for (int ni = 0; ni < 8; ++ni) {
                const int brow = ni * 16 + lo;
                const bf16x8 bv8 =
                    *(const bf16x8*)&wb[brow * 128 + ((g + 4 * ks) ^ (brow & 7)) * 8];
                acc[ni] = __builtin_amdgcn_mfma_f32_16x16x32_bf16(av[ks], bv8, acc[ni], 0, 0, 0);
            }
#pragma unroll
        for (int ni = 0; ni < 8; ++ni) {
            const float bc = biases[m][ni * 16 + lo];
#pragma unroll
            for (int r = 0; r < 4; ++r)
                outs[m][(m0 + w * 16 + g * 4 + r) * 128 + ni * 16 + lo] =
                    (__bf16)(acc[ni][r] + bc);
        }
        if (m == 0) {
            __syncthreads();  // W1 landed; Ws free
#pragma unroll
            for (int it = 0; it < 4; ++it)
                glds16(Wt + 2 * 16384 + (it * 8 + w) * 512 + l * 8,
                       &Ws[(it * 8 + w) * 512]);
        } else if (m == 1) {
            __syncthreads();  // W2 landed
        }
    }
}

// ---------------------------------------------------------------------------
// FUSED attention + O-projection + residual + LayerNorm1 (round-13 body).
// RESF32=false: residual (xb) is stored PRE-SWIZZLED -> swizzled scalar reads.
// ---------------------------------------------------------------------------
template <int WEIGHTS, bool RESF32>
__global__ __launch_bounds__(512) void attn_oproj(
    const __bf16* __restrict__ Qb, const __bf16* __restrict__ Kb,
    const __bf16* __restrict__ Vb, const float* __restrict__ mask,
    const __bf16* __restrict__ Wo, const float* __restrict__ bo,
    const void* __restrict__ resid, const float* __restrict__ gamma,
    const float* __restrict__ beta, __bf16* __restrict__ O1,
    float* __restrict__ wout, float* __restrict__ l1out)
{
    __shared__ __bf16 Kls[2][256 * 32];  // double-buffered, XOR-swizzled
    __shared__ __bf16 Vt[2][32][270];    // double-buffered V^T [d][key]
    __shared__ __bf16 Pl[8][16 * 64];    // per-wave quarter-P, swizzled
    __shared__ __bf16 Ctx[128 * 128];    // swizzled ctx tile
    __shared__ __bf16 Wos[128 * 128];    // swizzled Wo (async DMA)
    __shared__ float mb[256];

    const int t = threadIdx.x;
    const int w = t >> 6, l = t & 63, lo = l & 15, g = l >> 4;
    const int b = blockIdx.x & 127, strip = blockIdx.x >> 7;  // strip-major
    const size_t bbase = (size_t)b * 256 * 128;
    const int q0 = strip * 128 + w * 16;
    const int kswz = (lo ^ (lo >> 2)) & 3;

    // async: Wo -> Wos
#pragma unroll
    for (int it = 0; it < 4; ++it)
        glds16(Wo + (it * 8 + w) * 512 + l * 8, &Wos[(it * 8 + w) * 512]);

    // T14 K/V prefetch registers
    bf16x8 kpre[2], vpre[2];
    const int krow = t >> 2, kc = t & 3;
    const int vkey = t >> 2, vd0 = (t & 3) << 3;

    auto loadKV = [&](int h) {
#pragma unroll
        for (int p = 0; p < 2; ++p)
            kpre[p] = *(const bf16x8*)(Kb + bbase + (size_t)(p * 128 + krow) * 128 +
                                       h * 32 + kc * 8);
#pragma unroll
        for (int p = 0; p < 2; ++p)
            vpre[p] = *(const bf16x8*)(Vb + bbase + (size_t)(p * 128 + vkey) * 128 +
                                       h * 32 + vd0);
    };
    auto writeKV = [&](int buf) {
#pragma unroll
        for (int p = 0; p < 2; ++p) {
            const int row = p * 128 + krow;
            const int sw = (kc ^ ((row ^ (row >> 2)) & 3)) << 3;
            *(bf16x8*)&Kls[buf][row * 32 + sw] = kpre[p];
        }
#pragma unroll
        for (int p = 0; p < 2; ++p) {
            const int key = p * 128 + vkey;
#pragma unroll
            for (int i = 0; i < 8; ++i) Vt[buf][vd0 + i][key] = vpre[p][i];
        }
    };

    if (t < 256) mb[t] = mask[b * 256 + t] * (kNeg * kLog2e);
    if (WEIGHTS && blockIdx.x == 0 && t == 0) l1out[0] = 1024.0f;

    bf16x8 qfr[4];
#pragma unroll
    for (int h = 0; h < 4; ++h)
        qfr[h] = *(const bf16x8*)(Qb + bbase + (size_t)(q0 + lo) * 128 + h * 32 + g * 8);

    loadKV(0);
    writeKV(0);
    __syncthreads();

#pragma unroll
    for (int h = 0; h < 4; ++h) {
        const int cur = h & 1;
        f32x4 s[16];
        __builtin_amdgcn_s_setprio(1);
#pragma unroll
        for (int f = 0; f < 16; ++f) {
            const bf16x8 kf =
                *(const bf16x8*)&Kls[cur][(f * 16 + lo) * 32 + ((g ^ kswz) << 3)];
            s[f] = __builtin_amdgcn_mfma_f32_16x16x32_bf16(
                kf, qfr[h], f32x4{0.f, 0.f, 0.f, 0.f}, 0, 0, 0);
        }
        __builtin_amdgcn_s_setprio(0);

        if (h < 3) loadKV(h + 1);  // T14: issue next head's K/V now

        float ls = 0.f;
#pragma unroll
        for (int f = 0; f < 16; ++f) {
            const f32x4 mk = *(const f32x4*)&mb[f * 16 + g * 4];
#pragma unroll
            for (int r = 0; r < 4; ++r) {
                const float p = __builtin_amdgcn_exp2f(
                    s[f][r] * (kScale * kLog2e) + mk[r]);
                s[f][r] = p;
                ls += p;
            }
        }
        ls += __shfl_xor(ls, 16, 64);
        ls += __shfl_xor(ls, 32, 64);

        if constexpr (WEIGHTS) {
            if (strip == 1 && w == 7 && lo == 15) {
                const float inv = 1.f / ls;
                float* wrow = wout + ((size_t)b * 4 + h) * 256;
#pragma unroll
                for (int f = 0; f < 16; ++f)
#pragma unroll
                    for (int r = 0; r < 4; ++r)
                        wrow[f * 16 + g * 4 + r] = s[f][r] * inv;
            }
        }

        // stage next head's K/V into the IDLE buffer (hidden under PV)
        if (h < 3) writeKV(cur ^ 1);

        // PV in four quarter-P passes (64 keys each)
        f32x4 o[2] = {f32x4{0.f, 0.f, 0.f, 0.f}, f32x4{0.f, 0.f, 0.f, 0.f}};
#pragma unroll
        for (int qt = 0; qt < 4; ++qt) {
#pragma unroll
            for (int fl = 0; fl < 4; ++fl) {
                const int ff = qt * 4 + fl;
#pragma unroll
                for (int pr = 0; pr < 2; ++pr) {
                    bf16x2 pk;
                    pk[0] = (__bf16)s[ff][2 * pr];
                    pk[1] = (__bf16)s[ff][2 * pr + 1];
                    const int e = fl * 16 + 4 * g + 2 * pr;  // 0..63
                    const int addr =
                        lo * 64 + ((((e >> 3) ^ (lo & 7)) << 3) | (e & 7));
                    *(bf16x2*)&Pl[w][addr] = pk;
                }
            }
            __builtin_amdgcn_s_setprio(1);
#pragma unroll
            for (int ksl = 0; ksl < 2; ++ksl) {
                const int cc = ksl * 4 + g;
                const bf16x8 pa =
                    *(const bf16x8*)&Pl[w][lo * 64 + ((cc ^ (lo & 7)) << 3)];
#pragma unroll
                for (int nf = 0; nf < 2; ++nf) {
                    const bf16x8 bv =
                        *(const bf16x8*)&Vt[cur][nf * 16 + lo][(qt * 2 + ksl) * 32 + g * 8];
                    o[nf] = __builtin_amdgcn_mfma_f32_16x16x32_bf16(pa, bv, o[nf], 0, 0, 0);
                }
            }
            __builtin_amdgcn_s_setprio(0);
        }

        // normalized ctx -> swizzled LDS tile (cols h*32..h*32+31)
#pragma unroll
        for (int r = 0; r < 4; ++r) {
            const float inv = 1.f / __shfl(ls, 4 * g + r, 64);
            const int crow = w * 16 + g * 4 + r;
#pragma unroll
            for (int nf = 0; nf < 2; ++nf) {
                const int col = h * 32 + nf * 16 + lo;
                const int chunk = (col >> 3) ^ (crow & 7);
                Ctx[crow * 128 + (chunk << 3) + (col & 7)] = (__bf16)(o[nf][r] * inv);
            }
        }
        if (h < 3) __syncthreads();
    }

    // ---- O-projection + residual + LN1 (wave = 16 rows) ----
    const size_t m0 = (size_t)b * 256 + strip * 128;
    f32x4 acc[8];
#pragma unroll
    for (int ni = 0; ni < 8; ++ni) acc[ni] = f32x4{0.f, 0.f, 0.f, 0.f};

    const int arow = w * 16 + lo;
#pragma unroll
    for (int ks = 0; ks < 4; ++ks) {
        const bf16x8 av =
            *(const bf16x8*)&Ctx[arow * 128 + (((g + 4 * ks) ^ (arow & 7)) << 3)];
#pragma unroll
        for (int ni = 0; ni < 8; ++ni) {
            const int brow = ni * 16 + lo;
            const bf16x8 bv8 =
                *(const bf16x8*)&Wos[brow * 128 + (((g + 4 * ks) ^ (brow & 7)) << 3)];
            acc[ni] = __builtin_amdgcn_mfma_f32_16x16x32_bf16(av, bv8, acc[ni], 0, 0, 0);
        }
    }

    float bcol[8], ga[8], be[8];
#pragma unroll
    for (int ni = 0; ni < 8; ++ni) {
        bcol[ni] = bo[ni * 16 + lo];
        ga[ni] = gamma[ni * 16 + lo];
        be[ni] = beta[ni * 16 + lo];
    }

    float vv[4][8];
    float s[4] = {0, 0, 0, 0}, s2[4] = {0, 0, 0, 0};
#pragma unroll
    for (int r = 0; r < 4; ++r) {
        const size_t mm = m0 + w * 16 + g * 4 + r;
#pragma unroll
        for (int ni = 0; ni < 8; ++ni) {
            float rv;
            if constexpr (RESF32) {
                rv = ((const float*)resid)[mm * 128 + ni * 16 + lo];
            } else {
                // xb is pre-swizzled: element (mm, ni*16+lo)
                const int chunk = ((ni * 16 + lo) >> 3) ^ ((int)mm & 7);
                rv = (float)((const __bf16*)resid)[mm * 128 + chunk * 8 + (lo & 7)];
            }
            const float x = acc[ni][r] + bcol[ni] + rv;
            vv[r][ni] = x; s[r] += x; s2[r] += x * x;
        }
    }
#pragma unroll
    for (int r = 0; r < 4; ++r)
#pragma unroll
        for (int o = 1; o < 16; o <<= 1) {
            s[r] += __shfl_xor(s[r], o, 64);
            s2[r] += __shfl_xor(s2[r], o, 64);
        }
#pragma unroll
    for (int r = 0; r < 4; ++r) {
        const float mu = s[r] * (1.f / 128.f);
        const float var = s2[r] * (1.f / 128.f) - mu * mu;
        const float rs = rsqrtf(var + kEps);
        const size_t mm = m0 + w * 16 + g * 4 + r;
#pragma unroll
        for (int ni = 0; ni < 8; ++ni)
            O1[mm * 128 + ni * 16 + lo] =
                (__bf16)(ga[ni] * (vv[r][ni] - mu) * rs + be[ni]);
    }
}

// ---------------------------------------------------------------------------
// FUSED tree aggregation + residual + LayerNorm2 — SPLIT GRID (256 blocks):
// blocks 0..127  = tree-blocks: stage all 255 rows -> f32 LDS, per-wave
//                  barrier-free tree, LN + write rows 0..127.
// blocks 128..255 = leaf-blocks: rows 128..255 are all leaves (127..254) or
//                  the pass-through row 255 -> y = 2*o1, NO tree, streaming.
// Sibling pair (b, b+128) lands on the same XCD -> O1 reads L2-shared.
// xb (bf16 x for next layer) is written PRE-SWIZZLED for qkv's async DMA.
// ---------------------------------------------------------------------------
__global__ __launch_bounds__(1024) void tree_ln(
    const __bf16* __restrict__ o1, const float* __restrict__ gamma,
    const float* __restrict__ beta, float* __restrict__ xo,
    __bf16* __restrict__ xb, int wf32, int wbf16)
{
    __shared__ float e[255 * 132];
    const int isleaf = blockIdx.x >> 7;
    const int b = blockIdx.x & 127;
    const int t = threadIdx.x;
    const __bf16* ob = o1 + (size_t)b * 256 * 128;
    const int wv = t >> 6, lane = t & 63;
    const float2 gv = *(const float2*)(gamma + lane * 2);
    const float2 bb = *(const float2*)(beta + lane * 2);
    const int c = lane * 2;

    auto ln_store = [&](int row, float y0, float y1) {
        float s = y0 + y1, s2 = y0 * y0 + y1 * y1;
#pragma unroll
        for (int o = 1; o < 64; o <<= 1) {
            s += __shfl_xor(s, o, 64);
            s2 += __shfl_xor(s2, o, 64);
        }
        const float mu = s * (1.f / 128.f);
        const float var = s2 * (1.f / 128.f) - mu * mu;
        const float rs = rsqrtf(var + kEps);
        const float r0 = gv.x * (y0 - mu) * rs + bb.x;
        const float r1 = gv.y * (y1 - mu) * rs + bb.y;
        const size_t rowoff = ((size_t)b * 256 + row) * 128;
        if (wf32) {
            float2 o2; o2.x = r0; o2.y = r1;
            *(float2*)(xo + rowoff + c) = o2;
        }
        if (wbf16) {
            // pre-swizzled write: chunk = (c/8) ^ (row&7)
            const int chunk = (c >> 3) ^ (row & 7);
            bf16x2 ob2; ob2[0] = (__bf16)r0; ob2[1] = (__bf16)r1;
            *(bf16x2*)(xb + rowoff + chunk * 8 + (c & 7)) = ob2;
        }
    };

    if (isleaf) {
        // rows 128..255: all leaves or pass-through -> y = 2*o1, no tree
        for (int row = 128 + wv; row < 256; row += 16) {
            const bf16x2 v = *(const bf16x2*)(ob + (size_t)row * 128 + c);
            ln_store(row, 2.f * (float)v[0], 2.f * (float)v[1]);
        }
        return;
    }

    // ---- tree-block: stage all 255 rows -> f32 LDS ----
#pragma unroll
    for (int p = 0; p < 4; ++p) {
        const int ci = p * 1024 + t;
        if (ci < 4080) {
            const int row = ci >> 4, c8 = (ci & 15) * 8;
            const bf16x8 v = *(const bf16x8*)(ob + ci * 8);
            float* dst = &e[row * 132 + c8];
#pragma unroll
            for (int i = 0; i < 8; ++i) dst[i] = (float)v[i];
        }
    }
    __syncthreads();

    // per-wave barrier-free tree: wave wv -> cols wv*8..wv*8+7
    {
        const int col = wv * 8 + (lane & 7);
        const int nsub = lane >> 3;
        for (int lvl = 6; lvl >= 0; --lvl) {
            const int p0 = (1 << lvl) - 1;
            const int cnt = 1 << lvl;
            for (int base = 0; base < cnt; base += 8) {
                const int p = p0 + base + nsub;
                if (base + nsub < cnt) {
                    e[p * 132 + col] =
                        tanhf(e[(2 * p + 1) * 132 + col] + e[(2 * p + 2) * 132 + col]);
                }
            }
        }
    }
    __syncthreads();

    // LN + write rows 0..127 only
    for (int row = wv; row < 128; row += 16) {
        float y0, y1;
        if (row < 127) {
            // internal node: original o1 from global, tab from e
            const bf16x2 v = *(const bf16x2*)(ob + (size_t)row * 128 + c);
            y0 = (float)v[0] + e[row * 132 + c];
            y1 = (float)v[1] + e[row * 132 + c + 1];
        } else {
            // row 127 is a leaf: e still holds original o1
            y0 = 2.f * e[row * 132 + c];
            y1 = 2.f * e[row * 132 + c + 1];
        }
        ln_store(row, y0, y1);
    }
}

// ---------------------------------------------------------------------------
extern "C" void kernel_launch(void* const* d_in, const int* in_sizes, int n_in,
                              void* d_out, int out_size, void* d_ws, size_t ws_size,
                              hipStream_t stream)
{
    (void)in_sizes; (void)n_in; (void)out_size; (void)ws_size;

    const float* x_in = (const float*)d_in[0];
    const float* mask = (const float*)d_in[1];
    const float* Wq = (const float*)d_in[5];
    const float* bq = (const float*)d_in[6];
    const float* Wk = (const float*)d_in[7];
    const float* bk = (const float*)d_in[8];
    const float* Wv = (const float*)d_in[9];
    const float* bv = (const float*)d_in[10];
    const float* Wo = (const float*)d_in[11];
    const float* bo = (const float*)d_in[12];
    const float* g1 = (const float*)d_in[13];
    const float* b1 = (const float*)d_in[14];
    const float* g2 = (const float*)d_in[15];
    const float* b2 = (const float*)d_in[16];

    float* out_x = (float*)d_out;
    float* out_l1 = out_x + kSZ;
    float* out_w = out_l1 + 1;

    char* wsb = (char*)d_ws;
    __bf16* Qb = (__bf16*)wsb;
    __bf16* Kb = (__bf16*)(wsb + 1 * kSZ * 2);
    __bf16* Vb = (__bf16*)(wsb + 2 * kSZ * 2);
    __bf16* O1 = (__bf16*)(wsb + 3 * kSZ * 2);
    __bf16* xb = (__bf16*)(wsb + 4 * kSZ * 2);   // pre-swizzled bf16 x
    __bf16* Wt = (__bf16*)(wsb + 5 * kSZ * 2);   // 8 * 16384 bf16, pre-swizzled

    wtrans<<<8, 256, 0, stream>>>(Wq, Wk, Wv, Wo, Wt);

    // ---- layer 0 (f32 x_in) ----
    qkv_gemm<true><<<256, 512, 0, stream>>>(x_in, Wt, bq, bk, bv, Qb, Kb, Vb);
    attn_oproj<0, true><<<256, 512, 0, stream>>>(Qb, Kb, Vb, mask,
                                                 Wt + 3 * kD * kD, bo,
                                                 x_in, g1, b1, O1,
                                                 nullptr, nullptr);
    tree_ln<<<256, 1024, 0, stream>>>(O1, g2, b2, nullptr, xb, 0, 1);

    // ---- layer 1 (bf16 xb, pre-swizzled) ----
    const __bf16* WtL = Wt + 4 * kD * kD;
    qkv_gemm<false><<<256, 512, 0, stream>>>(xb, WtL, bq + kD, bk + kD, bv + kD,
                                             Qb, Kb, Vb);
    attn_oproj<1, false><<<256, 512, 0, stream>>>(Qb, Kb, Vb, mask,
                                                  WtL + 3 * kD * kD, bo + kD,
                                                  xb, g1 + kD, b1 + kD, O1,
                                                  out_w, out_l1);
    tree_ln<<<256, 1024, 0, stream>>>(O1, g2 + kD, b2 + kD, out_x, nullptr, 1, 0);
}

// Round 15
// 115.009 us; speedup vs baseline: 1.1623x; 1.0114x over previous
//
#include <hip/hip_runtime.h>
#include <math.h>

typedef __bf16 bf16x8 __attribute__((ext_vector_type(8)));
typedef __bf16 bf16x2 __attribute__((ext_vector_type(2)));
typedef float f32x4 __attribute__((ext_vector_type(4)));

namespace {
constexpr int kB = 128, kS = 256, kD = 128, kH = 4;
constexpr float kEps = 1e-6f;
constexpr float kScale = 0.17677669529663687f;  // 1/sqrt(32)
constexpr float kNeg = -1000000000.0f;
constexpr float kLog2e = 1.4426950408889634f;
constexpr size_t kSZ = (size_t)kB * kS * kD;    // 4,194,304
}

// ---------------------------------------------------------------------------
// global->LDS async DMA, 16 B/lane (dest = wave-uniform base + lane*16).
// ---------------------------------------------------------------------------
__device__ __forceinline__ void glds16(const void* g, void* l) {
    __builtin_amdgcn_global_load_lds(
        (const __attribute__((address_space(1))) unsigned int*)g,
        (__attribute__((address_space(3))) unsigned int*)l, 16, 0, 0);
}

// ---------------------------------------------------------------------------
// Weight transpose + convert + PRE-SWIZZLE:
// Wt[m][n*128 + ((k/8)^(n&7))*8 + k%8] = (bf16) W[m][k][n]
// ---------------------------------------------------------------------------
__global__ __launch_bounds__(256) void wtrans(
    const float* __restrict__ Wq, const float* __restrict__ Wk,
    const float* __restrict__ Wv, const float* __restrict__ Wo,
    __bf16* __restrict__ Wt)
{
    const int mtx = blockIdx.x & 3, l = blockIdx.x >> 2;
    const float* W = (mtx == 0 ? Wq : mtx == 1 ? Wk : mtx == 2 ? Wv : Wo) +
                     (size_t)l * kD * kD;
    __bf16* o = Wt + (size_t)blockIdx.x * kD * kD;
    for (int idx = threadIdx.x; idx < kD * kD; idx += 256) {
        const int k = idx >> 7, n = idx & 127;
        o[n * 128 + (((k >> 3) ^ (n & 7)) << 3) + (k & 7)] = (__bf16)W[idx];
    }
}

// ---------------------------------------------------------------------------
// Fused QKV GEMM, 64KB LDS, async W ping-pong, strip-major tiles (r13/r14).
// ---------------------------------------------------------------------------
template <bool F32A>
__global__ __launch_bounds__(512, 4) void qkv_gemm(
    const void* __restrict__ Av, const __bf16* __restrict__ Wt,
    const float* __restrict__ bq, const float* __restrict__ bk,
    const float* __restrict__ bv, __bf16* __restrict__ Qb,
    __bf16* __restrict__ Kb, __bf16* __restrict__ Vb)
{
    __shared__ __bf16 As[128 * 128];
    __shared__ __bf16 Ws[128 * 128];

    const int t = threadIdx.x;
    const int w = t >> 6, l = t & 63, lo = l & 15, g = l >> 4;
    const int tile = ((blockIdx.x & 127) << 1) | (blockIdx.x >> 7);
    const size_t m0 = (size_t)tile * 128;

    // async: W0 -> Ws
#pragma unroll
    for (int it = 0; it < 4; ++it)
        glds16(Wt + (it * 8 + w) * 512 + l * 8, &Ws[(it * 8 + w) * 512]);

    if constexpr (F32A) {
        // manual stage A (cvt f32->bf16), swizzled
#pragma unroll
        for (int p = 0; p < 4; ++p) {
            const int ci = p * 512 + t;
            const int row = ci >> 4, c = ci & 15;
            const float* src = (const float*)Av + (m0 + row) * 128 + c * 8;
            const float4 a0 = *(const float4*)src;
            const float4 a1 = *(const float4*)(src + 4);
            bf16x8 o;
            o[0] = (__bf16)a0.x; o[1] = (__bf16)a0.y; o[2] = (__bf16)a0.z; o[3] = (__bf16)a0.w;
            o[4] = (__bf16)a1.x; o[5] = (__bf16)a1.y; o[6] = (__bf16)a1.z; o[7] = (__bf16)a1.w;
            *(bf16x8*)&As[row * 128 + (c ^ (row & 7)) * 8] = o;
        }
    } else {
        // A is pre-swizzled bf16 -> linear async DMA
#pragma unroll
        for (int it = 0; it < 4; ++it)
            glds16((const __bf16*)Av + m0 * 128 + (it * 8 + w) * 512 + l * 8,
                   &As[(it * 8 + w) * 512]);
    }
    __syncthreads();   // A visible, W0 landed

    bf16x8 av[4];
    {
        const int arow = w * 16 + lo;
#pragma unroll
        for (int ks = 0; ks < 4; ++ks)
            av[ks] = *(const bf16x8*)&As[arow * 128 + ((g + 4 * ks) ^ (arow & 7)) * 8];
    }
    __syncthreads();   // As reusable as W buffer

    // async: W1 -> As (overlaps m=0 compute)
#pragma unroll
    for (int it = 0; it < 4; ++it)
        glds16(Wt + 16384 + (it * 8 + w) * 512 + l * 8, &As[(it * 8 + w) * 512]);

    const float* biases[3] = {bq, bk, bv};
    __bf16* outs[3] = {Qb, Kb, Vb};
    const __bf16* wbuf[3] = {Ws, As, Ws};

#pragma unroll
    for (int m = 0; m < 3; ++m) {
        const __bf16* wb = wbuf[m];
        f32x4 acc[8];
#pragma unroll
        for (int ni = 0; ni < 8; ++ni) acc[ni] = f32x4{0.f, 0.f, 0.f, 0.f};
#pragma unroll
        for (int ks = 0; ks < 4; ++ks)
#pragma unroll
            for (int ni = 0; ni < 8; ++ni) {
                const int brow = ni * 16 + lo;
                const bf16x8 bv8 =
                    *(const bf16x8*)&wb[brow * 128 + ((g + 4 * ks) ^ (brow & 7)) * 8];
                acc[ni] = __builtin_amdgcn_mfma_f32_16x16x32_bf16(av[ks], bv8, acc[ni], 0, 0, 0);
            }
#pragma unroll
        for (int ni = 0; ni < 8; ++ni) {
            const float bc = biases[m][ni * 16 + lo];
#pragma unroll
            for (int r = 0; r < 4; ++r)
                outs[m][(m0 + w * 16 + g * 4 + r) * 128 + ni * 16 + lo] =
                    (__bf16)(acc[ni][r] + bc);
        }
        if (m == 0) {
            __syncthreads();  // W1 landed; Ws free
#pragma unroll
            for (int it = 0; it < 4; ++it)
                glds16(Wt + 2 * 16384 + (it * 8 + w) * 512 + l * 8,
                       &Ws[(it * 8 + w) * 512]);
        } else if (m == 1) {
            __syncthreads();  // W2 landed
        }
    }
}

// ---------------------------------------------------------------------------
// FUSED attention + O-projection + residual + LayerNorm1 (round-13/14 body).
// RESF32=false: residual (xb) is stored PRE-SWIZZLED -> swizzled scalar reads.
// ---------------------------------------------------------------------------
template <int WEIGHTS, bool RESF32>
__global__ __launch_bounds__(512) void attn_oproj(
    const __bf16* __restrict__ Qb, const __bf16* __restrict__ Kb,
    const __bf16* __restrict__ Vb, const float* __restrict__ mask,
    const __bf16* __restrict__ Wo, const float* __restrict__ bo,
    const void* __restrict__ resid, const float* __restrict__ gamma,
    const float* __restrict__ beta, __bf16* __restrict__ O1,
    float* __restrict__ wout, float* __restrict__ l1out)
{
    __shared__ __bf16 Kls[2][256 * 32];  // double-buffered, XOR-swizzled
    __shared__ __bf16 Vt[2][32][270];    // double-buffered V^T [d][key]
    __shared__ __bf16 Pl[8][16 * 64];    // per-wave quarter-P, swizzled
    __shared__ __bf16 Ctx[128 * 128];    // swizzled ctx tile
    __shared__ __bf16 Wos[128 * 128];    // swizzled Wo (async DMA)
    __shared__ float mb[256];

    const int t = threadIdx.x;
    const int w = t >> 6, l = t & 63, lo = l & 15, g = l >> 4;
    const int b = blockIdx.x & 127, strip = blockIdx.x >> 7;  // strip-major
    const size_t bbase = (size_t)b * 256 * 128;
    const int q0 = strip * 128 + w * 16;
    const int kswz = (lo ^ (lo >> 2)) & 3;

    // async: Wo -> Wos
#pragma unroll
    for (int it = 0; it < 4; ++it)
        glds16(Wo + (it * 8 + w) * 512 + l * 8, &Wos[(it * 8 + w) * 512]);

    // T14 K/V prefetch registers
    bf16x8 kpre[2], vpre[2];
    const int krow = t >> 2, kc = t & 3;
    const int vkey = t >> 2, vd0 = (t & 3) << 3;

    auto loadKV = [&](int h) {
#pragma unroll
        for (int p = 0; p < 2; ++p)
            kpre[p] = *(const bf16x8*)(Kb + bbase + (size_t)(p * 128 + krow) * 128 +
                                       h * 32 + kc * 8);
#pragma unroll
        for (int p = 0; p < 2; ++p)
            vpre[p] = *(const bf16x8*)(Vb + bbase + (size_t)(p * 128 + vkey) * 128 +
                                       h * 32 + vd0);
    };
    auto writeKV = [&](int buf) {
#pragma unroll
        for (int p = 0; p < 2; ++p) {
            const int row = p * 128 + krow;
            const int sw = (kc ^ ((row ^ (row >> 2)) & 3)) << 3;
            *(bf16x8*)&Kls[buf][row * 32 + sw] = kpre[p];
        }
#pragma unroll
        for (int p = 0; p < 2; ++p) {
            const int key = p * 128 + vkey;
#pragma unroll
            for (int i = 0; i < 8; ++i) Vt[buf][vd0 + i][key] = vpre[p][i];
        }
    };

    if (t < 256) mb[t] = mask[b * 256 + t] * (kNeg * kLog2e);
    if (WEIGHTS && blockIdx.x == 0 && t == 0) l1out[0] = 1024.0f;

    bf16x8 qfr[4];
#pragma unroll
    for (int h = 0; h < 4; ++h)
        qfr[h] = *(const bf16x8*)(Qb + bbase + (size_t)(q0 + lo) * 128 + h * 32 + g * 8);

    loadKV(0);
    writeKV(0);
    __syncthreads();

#pragma unroll
    for (int h = 0; h < 4; ++h) {
        const int cur = h & 1;
        f32x4 s[16];
        __builtin_amdgcn_s_setprio(1);
#pragma unroll
        for (int f = 0; f < 16; ++f) {
            const bf16x8 kf =
                *(const bf16x8*)&Kls[cur][(f * 16 + lo) * 32 + ((g ^ kswz) << 3)];
            s[f] = __builtin_amdgcn_mfma_f32_16x16x32_bf16(
                kf, qfr[h], f32x4{0.f, 0.f, 0.f, 0.f}, 0, 0, 0);
        }
        __builtin_amdgcn_s_setprio(0);

        if (h < 3) loadKV(h + 1);  // T14: issue next head's K/V now

        float ls = 0.f;
#pragma unroll
        for (int f = 0; f < 16; ++f) {
            const f32x4 mk = *(const f32x4*)&mb[f * 16 + g * 4];
#pragma unroll
            for (int r = 0; r < 4; ++r) {
                const float p = __builtin_amdgcn_exp2f(
                    s[f][r] * (kScale * kLog2e) + mk[r]);
                s[f][r] = p;
                ls += p;
            }
        }
        ls += __shfl_xor(ls, 16, 64);
        ls += __shfl_xor(ls, 32, 64);

        if constexpr (WEIGHTS) {
            if (strip == 1 && w == 7 && lo == 15) {
                const float inv = 1.f / ls;
                float* wrow = wout + ((size_t)b * 4 + h) * 256;
#pragma unroll
                for (int f = 0; f < 16; ++f)
#pragma unroll
                    for (int r = 0; r < 4; ++r)
                        wrow[f * 16 + g * 4 + r] = s[f][r] * inv;
            }
        }

        // stage next head's K/V into the IDLE buffer (hidden under PV)
        if (h < 3) writeKV(cur ^ 1);

        // PV in four quarter-P passes (64 keys each)
        f32x4 o[2] = {f32x4{0.f, 0.f, 0.f, 0.f}, f32x4{0.f, 0.f, 0.f, 0.f}};
#pragma unroll
        for (int qt = 0; qt < 4; ++qt) {
#pragma unroll
            for (int fl = 0; fl < 4; ++fl) {
                const int ff = qt * 4 + fl;
#pragma unroll
                for (int pr = 0; pr < 2; ++pr) {
                    bf16x2 pk;
                    pk[0] = (__bf16)s[ff][2 * pr];
                    pk[1] = (__bf16)s[ff][2 * pr + 1];
                    const int e = fl * 16 + 4 * g + 2 * pr;  // 0..63
                    const int addr =
                        lo * 64 + ((((e >> 3) ^ (lo & 7)) << 3) | (e & 7));
                    *(bf16x2*)&Pl[w][addr] = pk;
                }
            }
            __builtin_amdgcn_s_setprio(1);
#pragma unroll
            for (int ksl = 0; ksl < 2; ++ksl) {
                const int cc = ksl * 4 + g;
                const bf16x8 pa =
                    *(const bf16x8*)&Pl[w][lo * 64 + ((cc ^ (lo & 7)) << 3)];
#pragma unroll
                for (int nf = 0; nf < 2; ++nf) {
                    const bf16x8 bv =
                        *(const bf16x8*)&Vt[cur][nf * 16 + lo][(qt * 2 + ksl) * 32 + g * 8];
                    o[nf] = __builtin_amdgcn_mfma_f32_16x16x32_bf16(pa, bv, o[nf], 0, 0, 0);
                }
            }
            __builtin_amdgcn_s_setprio(0);
        }

        // normalized ctx -> swizzled LDS tile (cols h*32..h*32+31)
#pragma unroll
        for (int r = 0; r < 4; ++r) {
            const float inv = 1.f / __shfl(ls, 4 * g + r, 64);
            const int crow = w * 16 + g * 4 + r;
#pragma unroll
            for (int nf = 0; nf < 2; ++nf) {
                const int col = h * 32 + nf * 16 + lo;
                const int chunk = (col >> 3) ^ (crow & 7);
                Ctx[crow * 128 + (chunk << 3) + (col & 7)] = (__bf16)(o[nf][r] * inv);
            }
        }
        if (h < 3) __syncthreads();
    }

    // ---- O-projection + residual + LN1 (wave = 16 rows) ----
    const size_t m0 = (size_t)b * 256 + strip * 128;
    f32x4 acc[8];
#pragma unroll
    for (int ni = 0; ni < 8; ++ni) acc[ni] = f32x4{0.f, 0.f, 0.f, 0.f};

    const int arow = w * 16 + lo;
#pragma unroll
    for (int ks = 0; ks < 4; ++ks) {
        const bf16x8 av =
            *(const bf16x8*)&Ctx[arow * 128 + (((g + 4 * ks) ^ (arow & 7)) << 3)];
#pragma unroll
        for (int ni = 0; ni < 8; ++ni) {
            const int brow = ni * 16 + lo;
            const bf16x8 bv8 =
                *(const bf16x8*)&Wos[brow * 128 + (((g + 4 * ks) ^ (brow & 7)) << 3)];
            acc[ni] = __builtin_amdgcn_mfma_f32_16x16x32_bf16(av, bv8, acc[ni], 0, 0, 0);
        }
    }

    float bcol[8], ga[8], be[8];
#pragma unroll
    for (int ni = 0; ni < 8; ++ni) {
        bcol[ni] = bo[ni * 16 + lo];
        ga[ni] = gamma[ni * 16 + lo];
        be[ni] = beta[ni * 16 + lo];
    }

    float vv[4][8];
    float s[4] = {0, 0, 0, 0}, s2[4] = {0, 0, 0, 0};
#pragma unroll
    for (int r = 0; r < 4; ++r) {
        const size_t mm = m0 + w * 16 + g * 4 + r;
#pragma unroll
        for (int ni = 0; ni < 8; ++ni) {
            float rv;
            if constexpr (RESF32) {
                rv = ((const float*)resid)[mm * 128 + ni * 16 + lo];
            } else {
                // xb is pre-swizzled: element (mm, ni*16+lo)
                const int chunk = ((ni * 16 + lo) >> 3) ^ ((int)mm & 7);
                rv = (float)((const __bf16*)resid)[mm * 128 + chunk * 8 + (lo & 7)];
            }
            const float x = acc[ni][r] + bcol[ni] + rv;
            vv[r][ni] = x; s[r] += x; s2[r] += x * x;
        }
    }
#pragma unroll
    for (int r = 0; r < 4; ++r)
#pragma unroll
        for (int o = 1; o < 16; o <<= 1) {
            s[r] += __shfl_xor(s[r], o, 64);
            s2[r] += __shfl_xor(s2[r], o, 64);
        }
#pragma unroll
    for (int r = 0; r < 4; ++r) {
        const float mu = s[r] * (1.f / 128.f);
        const float var = s2[r] * (1.f / 128.f) - mu * mu;
        const float rs = rsqrtf(var + kEps);
        const size_t mm = m0 + w * 16 + g * 4 + r;
#pragma unroll
        for (int ni = 0; ni < 8; ++ni)
            O1[mm * 128 + ni * 16 + lo] =
                (__bf16)(ga[ni] * (vv[r][ni] - mu) * rs + be[ni]);
    }
}

// ---------------------------------------------------------------------------
// FUSED tree aggregation + residual + LayerNorm2 — SPLIT GRID (256 blocks).
// NEW (r15): NO staging pass. Level 6 consumes leaf rows 127..254 directly
// from global (O1 is L2-hot) and writes internal nodes e[63..126]; e holds
// ONLY internal nodes 0..126 (67KB, was 131KB). Levels 5..0 per-wave
// barrier-free; LN rows 0..127 re-read O1 from global (row 127 = leaf).
// blocks 128..255 = leaf-blocks (rows 128..255: y = 2*o1, streaming).
// xb (bf16 x for next layer) is written PRE-SWIZZLED for qkv's async DMA.
// ---------------------------------------------------------------------------
__global__ __launch_bounds__(1024) void tree_ln(
    const __bf16* __restrict__ o1, const float* __restrict__ gamma,
    const float* __restrict__ beta, float* __restrict__ xo,
    __bf16* __restrict__ xb, int wf32, int wbf16)
{
    __shared__ float e[127 * 132];   // internal nodes only (67KB)
    const int isleaf = blockIdx.x >> 7;
    const int b = blockIdx.x & 127;
    const int t = threadIdx.x;
    const __bf16* ob = o1 + (size_t)b * 256 * 128;
    const int wv = t >> 6, lane = t & 63;
    const float2 gv = *(const float2*)(gamma + lane * 2);
    const float2 bb = *(const float2*)(beta + lane * 2);
    const int c = lane * 2;

    auto ln_store = [&](int row, float y0, float y1) {
        float s = y0 + y1, s2 = y0 * y0 + y1 * y1;
#pragma unroll
        for (int o = 1; o < 64; o <<= 1) {
            s += __shfl_xor(s, o, 64);
            s2 += __shfl_xor(s2, o, 64);
        }
        const float mu = s * (1.f / 128.f);
        const float var = s2 * (1.f / 128.f) - mu * mu;
        const float rs = rsqrtf(var + kEps);
        const float r0 = gv.x * (y0 - mu) * rs + bb.x;
        const float r1 = gv.y * (y1 - mu) * rs + bb.y;
        const size_t rowoff = ((size_t)b * 256 + row) * 128;
        if (wf32) {
            float2 o2; o2.x = r0; o2.y = r1;
            *(float2*)(xo + rowoff + c) = o2;
        }
        if (wbf16) {
            const int chunk = (c >> 3) ^ (row & 7);
            bf16x2 ob2; ob2[0] = (__bf16)r0; ob2[1] = (__bf16)r1;
            *(bf16x2*)(xb + rowoff + chunk * 8 + (c & 7)) = ob2;
        }
    };

    if (isleaf) {
        // rows 128..255: all leaves or pass-through -> y = 2*o1, no tree
        for (int row = 128 + wv; row < 256; row += 16) {
            const bf16x2 v = *(const bf16x2*)(ob + (size_t)row * 128 + c);
            ln_store(row, 2.f * (float)v[0], 2.f * (float)v[1]);
        }
        return;
    }

    // ---- level 6 straight from global: parents 63..126, children 127..254
    {
        const int p = 63 + (t >> 4);          // 1024 threads = 64 parents x 16
        const int cg = (t & 15) * 8;          // 8-col group
        const bf16x8 c1 = *(const bf16x8*)(ob + (size_t)(2 * p + 1) * 128 + cg);
        const bf16x8 c2 = *(const bf16x8*)(ob + (size_t)(2 * p + 2) * 128 + cg);
        f32x4 r0, r1;
#pragma unroll
        for (int i = 0; i < 4; ++i)
            r0[i] = tanhf((float)c1[i] + (float)c2[i]);
#pragma unroll
        for (int i = 0; i < 4; ++i)
            r1[i] = tanhf((float)c1[4 + i] + (float)c2[4 + i]);
        *(f32x4*)&e[p * 132 + cg] = r0;
        *(f32x4*)&e[p * 132 + cg + 4] = r1;
    }
    __syncthreads();

    // per-wave barrier-free tree, levels 5..0: wave wv -> cols wv*8..wv*8+7
    {
        const int col = wv * 8 + (lane & 7);
        const int nsub = lane >> 3;
        for (int lvl = 5; lvl >= 0; --lvl) {
            const int p0 = (1 << lvl) - 1;
            const int cnt = 1 << lvl;
            for (int base = 0; base < cnt; base += 8) {
                const int p = p0 + base + nsub;
                if (base + nsub < cnt) {
                    e[p * 132 + col] =
                        tanhf(e[(2 * p + 1) * 132 + col] + e[(2 * p + 2) * 132 + col]);
                }
            }
        }
    }
    __syncthreads();

    // LN + write rows 0..127 (row 127 is a leaf -> y = 2*o1 from global)
    for (int row = wv; row < 128; row += 16) {
        const bf16x2 v = *(const bf16x2*)(ob + (size_t)row * 128 + c);
        float y0, y1;
        if (row < 127) {
            y0 = (float)v[0] + e[row * 132 + c];
            y1 = (float)v[1] + e[row * 132 + c + 1];
        } else {
            y0 = 2.f * (float)v[0];
            y1 = 2.f * (float)v[1];
        }
        ln_store(row, y0, y1);
    }
}

// ---------------------------------------------------------------------------
extern "C" void kernel_launch(void* const* d_in, const int* in_sizes, int n_in,
                              void* d_out, int out_size, void* d_ws, size_t ws_size,
                              hipStream_t stream)
{
    (void)in_sizes; (void)n_in; (void)out_size; (void)ws_size;

    const float* x_in = (const float*)d_in[0];
    const float* mask = (const float*)d_in[1];
    const float* Wq = (const float*)d_in[5];
    const float* bq = (const float*)d_in[6];
    const float* Wk = (const float*)d_in[7];
    const float* bk = (const float*)d_in[8];
    const float* Wv = (const float*)d_in[9];
    const float* bv = (const float*)d_in[10];
    const float* Wo = (const float*)d_in[11];
    const float* bo = (const float*)d_in[12];
    const float* g1 = (const float*)d_in[13];
    const float* b1 = (const float*)d_in[14];
    const float* g2 = (const float*)d_in[15];
    const float* b2 = (const float*)d_in[16];

    float* out_x = (float*)d_out;
    float* out_l1 = out_x + kSZ;
    float* out_w = out_l1 + 1;

    char* wsb = (char*)d_ws;
    __bf16* Qb = (__bf16*)wsb;
    __bf16* Kb = (__bf16*)(wsb + 1 * kSZ * 2);
    __bf16* Vb = (__bf16*)(wsb + 2 * kSZ * 2);
    __bf16* O1 = (__bf16*)(wsb + 3 * kSZ * 2);
    __bf16* xb = (__bf16*)(wsb + 4 * kSZ * 2);   // pre-swizzled bf16 x
    __bf16* Wt = (__bf16*)(wsb + 5 * kSZ * 2);   // 8 * 16384 bf16, pre-swizzled

    wtrans<<<8, 256, 0, stream>>>(Wq, Wk, Wv, Wo, Wt);

    // ---- layer 0 (f32 x_in) ----
    qkv_gemm<true><<<256, 512, 0, stream>>>(x_in, Wt, bq, bk, bv, Qb, Kb, Vb);
    attn_oproj<0, true><<<256, 512, 0, stream>>>(Qb, Kb, Vb, mask,
                                                 Wt + 3 * kD * kD, bo,
                                                 x_in, g1, b1, O1,
                                                 nullptr, nullptr);
    tree_ln<<<256, 1024, 0, stream>>>(O1, g2, b2, nullptr, xb, 0, 1);

    // ---- layer 1 (bf16 xb, pre-swizzled) ----
    const __bf16* WtL = Wt + 4 * kD * kD;
    qkv_gemm<false><<<256, 512, 0, stream>>>(xb, WtL, bq + kD, bk + kD, bv + kD,
                                             Qb, Kb, Vb);
    attn_oproj<1, false><<<256, 512, 0, stream>>>(Qb, Kb, Vb, mask,
                                                  WtL + 3 * kD * kD, bo + kD,
                                                  xb, g1 + kD, b1 + kD, O1,
                                                  out_w, out_l1);
    tree_ln<<<256, 1024, 0, stream>>>(O1, g2 + kD, b2 + kD, out_x, nullptr, 1, 0);
}

// Round 16
// 105.539 us; speedup vs baseline: 1.2666x; 1.0897x over previous
//
#include <hip/hip_runtime.h>
#include <math.h>

typedef __bf16 bf16x8 __attribute__((ext_vector_type(8)));
typedef __bf16 bf16x4 __attribute__((ext_vector_type(4)));
typedef __bf16 bf16x2 __attribute__((ext_vector_type(2)));
typedef float f32x4 __attribute__((ext_vector_type(4)));

namespace {
constexpr int kB = 128, kS = 256, kD = 128, kH = 4;
constexpr float kEps = 1e-6f;
constexpr float kScale = 0.17677669529663687f;  // 1/sqrt(32)
constexpr float kNeg = -1000000000.0f;
constexpr float kLog2e = 1.4426950408889634f;
constexpr size_t kSZ = (size_t)kB * kS * kD;    // 4,194,304
}

// ---------------------------------------------------------------------------
// global->LDS async DMA, 16 B/lane.
// ---------------------------------------------------------------------------
__device__ __forceinline__ void glds16(const void* g, void* l) {
    __builtin_amdgcn_global_load_lds(
        (const __attribute__((address_space(1))) unsigned int*)g,
        (__attribute__((address_space(3))) unsigned int*)l, 16, 0, 0);
}

// ---------------------------------------------------------------------------
// Weight transpose + convert + FRAGMENT-MAJOR packing:
// frag(ni,ks)[lane l][j] = W^T[ni*16 + (l&15)][((l>>4) + 4*ks)*8 + j]
// packed at Wt[m][((ni*4+ks)*64 + l)*8 + j]. A wave's fragment load is one
// contiguous, coalesced 1KB read (16B/lane) straight from global (L1/L2-hot).
// ---------------------------------------------------------------------------
__global__ __launch_bounds__(256) void wtrans(
    const float* __restrict__ Wq, const float* __restrict__ Wk,
    const float* __restrict__ Wv, const float* __restrict__ Wo,
    __bf16* __restrict__ Wt)
{
    const int mtx = blockIdx.x & 3, l = blockIdx.x >> 2;
    const float* W = (mtx == 0 ? Wq : mtx == 1 ? Wk : mtx == 2 ? Wv : Wo) +
                     (size_t)l * kD * kD;
    __bf16* o = Wt + (size_t)blockIdx.x * kD * kD;
    for (int idx = threadIdx.x; idx < kD * kD; idx += 256) {
        const int k = idx >> 7, n = idx & 127;
        const int lo = n & 15, ni = n >> 4;
        const int j = k & 7, tt = k >> 3, g = tt & 3, ks = tt >> 2;
        o[((ni * 4 + ks) * 64 + g * 16 + lo) * 8 + j] = (__bf16)W[idx];
    }
}

// ---------------------------------------------------------------------------
// MEGA-KERNEL: QKV-GEMM + attention + O-projection + residual + LN1.
// Grid 256 strip-major (b = bid&127, strip = bid>>7); 512 thr = 8 waves.
// Xs = full batch x (256x128 bf16, row-XOR-swizzled) staged once (64KB).
// Per head: wave produces K_h/V_h for 32 token rows + Q_h for its 16 q rows
// via MFMA from Xs + fragment-major W (global, coalesced). Q/K/V never
// touch HBM. Consume phase = round-15 known-good QK^T/softmax/PV/ctx.
// Epilogue: oproj (Wo fragments from global) + resid from Xs + LN1 -> O1.
// LDS total ~154KB. WEIGHTS: q=255 wave emits softmax rows; l1 = 1024.
// ---------------------------------------------------------------------------
template <int WEIGHTS, bool F32X>
__global__ __launch_bounds__(512) void mega_attn(
    const void* __restrict__ xsrc, const __bf16* __restrict__ Wp,
    const float* __restrict__ bq, const float* __restrict__ bk,
    const float* __restrict__ bv, const float* __restrict__ bo,
    const float* __restrict__ mask, const float* __restrict__ gamma,
    const float* __restrict__ beta, __bf16* __restrict__ O1,
    float* __restrict__ wout, float* __restrict__ l1out)
{
    __shared__ __bf16 Xs[256 * 128];   // 64KB swizzled x (also the residual)
    __shared__ __bf16 Kls[256 * 32];   // 16KB, XOR-swizzled chunks
    __shared__ __bf16 Vt[32][276];     // 17.25KB V^T (stride 276: aligned+spread)
    __shared__ __bf16 Pl[8][16 * 64];  // 16KB per-wave quarter-P
    __shared__ __bf16 Qs[8][16 * 32];  // 8KB per-wave Q_h (16q x 32d)
    __shared__ __bf16 Ctx[128 * 128];  // 32KB swizzled ctx
    __shared__ float mb[256];

    const int t = threadIdx.x;
    const int w = t >> 6, l = t & 63, lo = l & 15, g = l >> 4;
    const int b = blockIdx.x & 127, strip = blockIdx.x >> 7;
    const int q0 = strip * 128 + w * 16;      // batch-local first q of wave
    const int tk0 = w * 32;                   // wave's K/V token rows
    const int kswz = (lo ^ (lo >> 2)) & 3;

    const __bf16* Wqp = Wp;
    const __bf16* Wkp = Wp + 16384;
    const __bf16* Wvp = Wp + 2 * 16384;
    const __bf16* Wop = Wp + 3 * 16384;

    // ---- stage Xs (full batch, swizzled) ----
    if constexpr (F32X) {
#pragma unroll
        for (int p = 0; p < 8; ++p) {
            const int ci = p * 512 + t;        // 0..4095
            const int row = ci >> 4, c = ci & 15;
            const float* src = (const float*)xsrc +
                               ((size_t)b * 256 + row) * 128 + c * 8;
            const float4 a0 = *(const float4*)src;
            const float4 a1 = *(const float4*)(src + 4);
            bf16x8 o;
            o[0] = (__bf16)a0.x; o[1] = (__bf16)a0.y; o[2] = (__bf16)a0.z; o[3] = (__bf16)a0.w;
            o[4] = (__bf16)a1.x; o[5] = (__bf16)a1.y; o[6] = (__bf16)a1.z; o[7] = (__bf16)a1.w;
            *(bf16x8*)&Xs[row * 128 + ((c ^ (row & 7)) << 3)] = o;
        }
    } else {
        // xb is pre-swizzled -> linear async DMA
#pragma unroll
        for (int it = 0; it < 8; ++it)
            glds16((const __bf16*)xsrc + (size_t)b * 32768 + (it * 8 + w) * 512 + l * 8,
                   &Xs[(it * 8 + w) * 512]);
    }
    if (t < 256) mb[t] = mask[b * 256 + t] * (kNeg * kLog2e);
    if (WEIGHTS && blockIdx.x == 0 && t == 0) l1out[0] = 1024.0f;
    __syncthreads();

    // fragment helpers
    auto wfrag = [&](const __bf16* W, int ni, int ks) {
        return *(const bf16x8*)(W + (((ni * 4 + ks) * 64 + l) << 3));
    };
    auto xfrag = [&](int row, int ks) {
        return *(const bf16x8*)&Xs[row * 128 + (((g + 4 * ks) ^ (row & 7)) << 3)];
    };

#pragma unroll
    for (int h = 0; h < 4; ++h) {
        // ======== PRODUCE K_h, V_h, Q_h ========
        bf16x8 xa[2][4];
#pragma unroll
        for (int mi = 0; mi < 2; ++mi)
#pragma unroll
            for (int ks = 0; ks < 4; ++ks)
                xa[mi][ks] = xfrag(tk0 + mi * 16 + lo, ks);

        f32x4 kacc[2][2], vacc[2][2];
#pragma unroll
        for (int i = 0; i < 2; ++i)
#pragma unroll
            for (int j2 = 0; j2 < 2; ++j2) {
                kacc[i][j2] = f32x4{0.f, 0.f, 0.f, 0.f};
                vacc[i][j2] = f32x4{0.f, 0.f, 0.f, 0.f};
            }
#pragma unroll
        for (int ks = 0; ks < 4; ++ks) {
            const bf16x8 wk0 = wfrag(Wkp, 2 * h, ks);
            const bf16x8 wk1 = wfrag(Wkp, 2 * h + 1, ks);
            const bf16x8 wv0 = wfrag(Wvp, 2 * h, ks);
            const bf16x8 wv1 = wfrag(Wvp, 2 * h + 1, ks);
            // K swapped (A=W rows d, B=x tokens): lane holds fixed key, 4 consec d
            kacc[0][0] = __builtin_amdgcn_mfma_f32_16x16x32_bf16(wk0, xa[0][ks], kacc[0][0], 0, 0, 0);
            kacc[0][1] = __builtin_amdgcn_mfma_f32_16x16x32_bf16(wk0, xa[1][ks], kacc[0][1], 0, 0, 0);
            kacc[1][0] = __builtin_amdgcn_mfma_f32_16x16x32_bf16(wk1, xa[0][ks], kacc[1][0], 0, 0, 0);
            kacc[1][1] = __builtin_amdgcn_mfma_f32_16x16x32_bf16(wk1, xa[1][ks], kacc[1][1], 0, 0, 0);
            // V natural (A=x tokens, B=W cols d): lane holds fixed d, 4 consec keys
            vacc[0][0] = __builtin_amdgcn_mfma_f32_16x16x32_bf16(xa[0][ks], wv0, vacc[0][0], 0, 0, 0);
            vacc[1][0] = __builtin_amdgcn_mfma_f32_16x16x32_bf16(xa[1][ks], wv0, vacc[1][0], 0, 0, 0);
            vacc[0][1] = __builtin_amdgcn_mfma_f32_16x16x32_bf16(xa[0][ks], wv1, vacc[0][1], 0, 0, 0);
            vacc[1][1] = __builtin_amdgcn_mfma_f32_16x16x32_bf16(xa[1][ks], wv1, vacc[1][1], 0, 0, 0);
        }
        f32x4 qacc[2] = {f32x4{0.f, 0.f, 0.f, 0.f}, f32x4{0.f, 0.f, 0.f, 0.f}};
#pragma unroll
        for (int ks = 0; ks < 4; ++ks) {
            const bf16x8 xq = xfrag(q0 + lo, ks);
            qacc[0] = __builtin_amdgcn_mfma_f32_16x16x32_bf16(xq, wfrag(Wqp, 2 * h, ks), qacc[0], 0, 0, 0);
            qacc[1] = __builtin_amdgcn_mfma_f32_16x16x32_bf16(xq, wfrag(Wqp, 2 * h + 1, ks), qacc[1], 0, 0, 0);
        }

        // K -> Kls (vector bf16x4, swizzled chunks; key = tk0+tj*16+lo)
#pragma unroll
        for (int dm = 0; dm < 2; ++dm) {
            const f32x4 bkv = *(const f32x4*)(bk + h * 32 + dm * 16 + 4 * g);
            const int pos = ((dm * 2 + (g >> 1)) ^ kswz) << 3;
            const int sub = (4 * g) & 7;
#pragma unroll
            for (int tj = 0; tj < 2; ++tj) {
                bf16x4 kv;
#pragma unroll
                for (int r = 0; r < 4; ++r) kv[r] = (__bf16)(kacc[dm][tj][r] + bkv[r]);
                const int key = tk0 + tj * 16 + lo;
                *(bf16x4*)&Kls[key * 32 + pos + sub] = kv;
            }
        }
        // V -> Vt (vector bf16x4; d = nj*16+lo, keys consecutive)
#pragma unroll
        for (int nj = 0; nj < 2; ++nj) {
            const float bvv = bv[h * 32 + nj * 16 + lo];
#pragma unroll
            for (int mi = 0; mi < 2; ++mi) {
                bf16x4 vv4;
#pragma unroll
                for (int r = 0; r < 4; ++r) vv4[r] = (__bf16)(vacc[mi][nj][r] + bvv);
                *(bf16x4*)&Vt[nj * 16 + lo][tk0 + mi * 16 + 4 * g] = vv4;
            }
        }
        // Q -> Qs (scalar; q_local = 4g+r, d = nj*16+lo)
#pragma unroll
        for (int nj = 0; nj < 2; ++nj) {
            const float bqv = bq[h * 32 + nj * 16 + lo];
#pragma unroll
            for (int r = 0; r < 4; ++r)
                Qs[w][(4 * g + r) * 32 + nj * 16 + lo] = (__bf16)(qacc[nj][r] + bqv);
        }
        __syncthreads();

        // ======== CONSUME: QK^T -> softmax -> PV -> ctx ========
        const bf16x8 qf = *(const bf16x8*)&Qs[w][lo * 32 + g * 8];
        f32x4 s[16];
        __builtin_amdgcn_s_setprio(1);
#pragma unroll
        for (int f = 0; f < 16; ++f) {
            const bf16x8 kf =
                *(const bf16x8*)&Kls[(f * 16 + lo) * 32 + ((g ^ kswz) << 3)];
            s[f] = __builtin_amdgcn_mfma_f32_16x16x32_bf16(
                kf, qf, f32x4{0.f, 0.f, 0.f, 0.f}, 0, 0, 0);
        }
        __builtin_amdgcn_s_setprio(0);

        float ls = 0.f;
#pragma unroll
        for (int f = 0; f < 16; ++f) {
            const f32x4 mk = *(const f32x4*)&mb[f * 16 + g * 4];
#pragma unroll
            for (int r = 0; r < 4; ++r) {
                const float p = __builtin_amdgcn_exp2f(
                    s[f][r] * (kScale * kLog2e) + mk[r]);
                s[f][r] = p;
                ls += p;
            }
        }
        ls += __shfl_xor(ls, 16, 64);
        ls += __shfl_xor(ls, 32, 64);

        if constexpr (WEIGHTS) {
            if (strip == 1 && w == 7 && lo == 15) {
                const float inv = 1.f / ls;
                float* wrow = wout + ((size_t)b * 4 + h) * 256;
#pragma unroll
                for (int f = 0; f < 16; ++f)
#pragma unroll
                    for (int r = 0; r < 4; ++r)
                        wrow[f * 16 + g * 4 + r] = s[f][r] * inv;
            }
        }

        // PV in four quarter-P passes (64 keys each)
        f32x4 o[2] = {f32x4{0.f, 0.f, 0.f, 0.f}, f32x4{0.f, 0.f, 0.f, 0.f}};
#pragma unroll
        for (int qt = 0; qt < 4; ++qt) {
#pragma unroll
            for (int fl = 0; fl < 4; ++fl) {
                const int ff = qt * 4 + fl;
#pragma unroll
                for (int pr = 0; pr < 2; ++pr) {
                    bf16x2 pk;
                    pk[0] = (__bf16)s[ff][2 * pr];
                    pk[1] = (__bf16)s[ff][2 * pr + 1];
                    const int e = fl * 16 + 4 * g + 2 * pr;
                    const int addr =
                        lo * 64 + ((((e >> 3) ^ (lo & 7)) << 3) | (e & 7));
                    *(bf16x2*)&Pl[w][addr] = pk;
                }
            }
            __builtin_amdgcn_s_setprio(1);
#pragma unroll
            for (int ksl = 0; ksl < 2; ++ksl) {
                const int cc = ksl * 4 + g;
                const bf16x8 pa =
                    *(const bf16x8*)&Pl[w][lo * 64 + ((cc ^ (lo & 7)) << 3)];
#pragma unroll
                for (int nf = 0; nf < 2; ++nf) {
                    const bf16x8 bvv =
                        *(const bf16x8*)&Vt[nf * 16 + lo][(qt * 2 + ksl) * 32 + g * 8];
                    o[nf] = __builtin_amdgcn_mfma_f32_16x16x32_bf16(pa, bvv, o[nf], 0, 0, 0);
                }
            }
            __builtin_amdgcn_s_setprio(0);
        }

        // normalized ctx -> swizzled LDS tile (cols h*32..h*32+31)
#pragma unroll
        for (int r = 0; r < 4; ++r) {
            const float inv = 1.f / __shfl(ls, 4 * g + r, 64);
            const int crow = w * 16 + g * 4 + r;
#pragma unroll
            for (int nf = 0; nf < 2; ++nf) {
                const int col = h * 32 + nf * 16 + lo;
                const int chunk = (col >> 3) ^ (crow & 7);
                Ctx[crow * 128 + (chunk << 3) + (col & 7)] = (__bf16)(o[nf][r] * inv);
            }
        }
        if (h < 3) __syncthreads();  // Kls/Vt reads done before next produce
    }

    // ======== O-projection + residual + LN1 ========
    const size_t m0 = (size_t)b * 256 + strip * 128;
    f32x4 acc[8];
#pragma unroll
    for (int ni = 0; ni < 8; ++ni) acc[ni] = f32x4{0.f, 0.f, 0.f, 0.f};

    const int arow = w * 16 + lo;
#pragma unroll
    for (int ks = 0; ks < 4; ++ks) {
        const bf16x8 av =
            *(const bf16x8*)&Ctx[arow * 128 + (((g + 4 * ks) ^ (arow & 7)) << 3)];
#pragma unroll
        for (int ni = 0; ni < 8; ++ni)
            acc[ni] = __builtin_amdgcn_mfma_f32_16x16x32_bf16(
                av, wfrag(Wop, ni, ks), acc[ni], 0, 0, 0);
    }

    float bcol[8], ga[8], be[8];
#pragma unroll
    for (int ni = 0; ni < 8; ++ni) {
        bcol[ni] = bo[ni * 16 + lo];
        ga[ni] = gamma[ni * 16 + lo];
        be[ni] = beta[ni * 16 + lo];
    }

    float vv[4][8];
    float s[4] = {0, 0, 0, 0}, s2[4] = {0, 0, 0, 0};
#pragma unroll
    for (int r = 0; r < 4; ++r) {
        const int local = strip * 128 + w * 16 + g * 4 + r;
#pragma unroll
        for (int ni = 0; ni < 8; ++ni) {
            const int col = ni * 16 + lo;
            const int chunk = (col >> 3) ^ (local & 7);
            const float rv = (float)Xs[local * 128 + (chunk << 3) + (col & 7)];
            const float x = acc[ni][r] + bcol[ni] + rv;
            vv[r][ni] = x; s[r] += x; s2[r] += x * x;
        }
    }
#pragma unroll
    for (int r = 0; r < 4; ++r)
#pragma unroll
        for (int o = 1; o < 16; o <<= 1) {
            s[r] += __shfl_xor(s[r], o, 64);
            s2[r] += __shfl_xor(s2[r], o, 64);
        }
#pragma unroll
    for (int r = 0; r < 4; ++r) {
        const float mu = s[r] * (1.f / 128.f);
        const float var = s2[r] * (1.f / 128.f) - mu * mu;
        const float rs = rsqrtf(var + kEps);
        const size_t mm = m0 + w * 16 + g * 4 + r;
#pragma unroll
        for (int ni = 0; ni < 8; ++ni)
            O1[mm * 128 + ni * 16 + lo] =
                (__bf16)(ga[ni] * (vv[r][ni] - mu) * rs + be[ni]);
    }
}

// ---------------------------------------------------------------------------
// FUSED tree aggregation + residual + LayerNorm2 (round-15 known-good).
// ---------------------------------------------------------------------------
__global__ __launch_bounds__(1024) void tree_ln(
    const __bf16* __restrict__ o1, const float* __restrict__ gamma,
    const float* __restrict__ beta, float* __restrict__ xo,
    __bf16* __restrict__ xb, int wf32, int wbf16)
{
    __shared__ float e[127 * 132];   // internal nodes only
    const int isleaf = blockIdx.x >> 7;
    const int b = blockIdx.x & 127;
    const int t = threadIdx.x;
    const __bf16* ob = o1 + (size_t)b * 256 * 128;
    const int wv = t >> 6, lane = t & 63;
    const float2 gv = *(const float2*)(gamma + lane * 2);
    const float2 bb = *(const float2*)(beta + lane * 2);
    const int c = lane * 2;

    auto ln_store = [&](int row, float y0, float y1) {
        float s = y0 + y1, s2 = y0 * y0 + y1 * y1;
#pragma unroll
        for (int o = 1; o < 64; o <<= 1) {
            s += __shfl_xor(s, o, 64);
            s2 += __shfl_xor(s2, o, 64);
        }
        const float mu = s * (1.f / 128.f);
        const float var = s2 * (1.f / 128.f) - mu * mu;
        const float rs = rsqrtf(var + kEps);
        const float r0 = gv.x * (y0 - mu) * rs + bb.x;
        const float r1 = gv.y * (y1 - mu) * rs + bb.y;
        const size_t rowoff = ((size_t)b * 256 + row) * 128;
        if (wf32) {
            float2 o2; o2.x = r0; o2.y = r1;
            *(float2*)(xo + rowoff + c) = o2;
        }
        if (wbf16) {
            const int chunk = (c >> 3) ^ (row & 7);
            bf16x2 ob2; ob2[0] = (__bf16)r0; ob2[1] = (__bf16)r1;
            *(bf16x2*)(xb + rowoff + chunk * 8 + (c & 7)) = ob2;
        }
    };

    if (isleaf) {
        for (int row = 128 + wv; row < 256; row += 16) {
            const bf16x2 v = *(const bf16x2*)(ob + (size_t)row * 128 + c);
            ln_store(row, 2.f * (float)v[0], 2.f * (float)v[1]);
        }
        return;
    }

    // level 6 straight from global: parents 63..126, children 127..254
    {
        const int p = 63 + (t >> 4);
        const int cg = (t & 15) * 8;
        const bf16x8 c1 = *(const bf16x8*)(ob + (size_t)(2 * p + 1) * 128 + cg);
        const bf16x8 c2 = *(const bf16x8*)(ob + (size_t)(2 * p + 2) * 128 + cg);
        f32x4 r0, r1;
#pragma unroll
        for (int i = 0; i < 4; ++i)
            r0[i] = tanhf((float)c1[i] + (float)c2[i]);
#pragma unroll
        for (int i = 0; i < 4; ++i)
            r1[i] = tanhf((float)c1[4 + i] + (float)c2[4 + i]);
        *(f32x4*)&e[p * 132 + cg] = r0;
        *(f32x4*)&e[p * 132 + cg + 4] = r1;
    }
    __syncthreads();

    {
        const int col = wv * 8 + (lane & 7);
        const int nsub = lane >> 3;
        for (int lvl = 5; lvl >= 0; --lvl) {
            const int p0 = (1 << lvl) - 1;
            const int cnt = 1 << lvl;
            for (int base = 0; base < cnt; base += 8) {
                const int p = p0 + base + nsub;
                if (base + nsub < cnt) {
                    e[p * 132 + col] =
                        tanhf(e[(2 * p + 1) * 132 + col] + e[(2 * p + 2) * 132 + col]);
                }
            }
        }
    }
    __syncthreads();

    for (int row = wv; row < 128; row += 16) {
        const bf16x2 v = *(const bf16x2*)(ob + (size_t)row * 128 + c);
        float y0, y1;
        if (row < 127) {
            y0 = (float)v[0] + e[row * 132 + c];
            y1 = (float)v[1] + e[row * 132 + c + 1];
        } else {
            y0 = 2.f * (float)v[0];
            y1 = 2.f * (float)v[1];
        }
        ln_store(row, y0, y1);
    }
}

// ---------------------------------------------------------------------------
extern "C" void kernel_launch(void* const* d_in, const int* in_sizes, int n_in,
                              void* d_out, int out_size, void* d_ws, size_t ws_size,
                              hipStream_t stream)
{
    (void)in_sizes; (void)n_in; (void)out_size; (void)ws_size;

    const float* x_in = (const float*)d_in[0];
    const float* mask = (const float*)d_in[1];
    const float* Wq = (const float*)d_in[5];
    const float* bq = (const float*)d_in[6];
    const float* Wk = (const float*)d_in[7];
    const float* bk = (const float*)d_in[8];
    const float* Wv = (const float*)d_in[9];
    const float* bv = (const float*)d_in[10];
    const float* Wo = (const float*)d_in[11];
    const float* bo = (const float*)d_in[12];
    const float* g1 = (const float*)d_in[13];
    const float* b1 = (const float*)d_in[14];
    const float* g2 = (const float*)d_in[15];
    const float* b2 = (const float*)d_in[16];

    float* out_x = (float*)d_out;
    float* out_l1 = out_x + kSZ;
    float* out_w = out_l1 + 1;

    char* wsb = (char*)d_ws;
    __bf16* O1 = (__bf16*)wsb;                   // 8MB
    __bf16* xb = (__bf16*)(wsb + kSZ * 2);       // 8MB, pre-swizzled bf16 x
    __bf16* Wt = (__bf16*)(wsb + 2 * kSZ * 2);   // 8 * 16384 bf16, frag-major

    wtrans<<<8, 256, 0, stream>>>(Wq, Wk, Wv, Wo, Wt);

    // ---- layer 0 (f32 x_in) ----
    mega_attn<0, true><<<256, 512, 0, stream>>>(x_in, Wt, bq, bk, bv, bo,
                                                mask, g1, b1, O1,
                                                nullptr, nullptr);
    tree_ln<<<256, 1024, 0, stream>>>(O1, g2, b2, nullptr, xb, 0, 1);

    // ---- layer 1 (bf16 xb, pre-swizzled) ----
    mega_attn<1, false><<<256, 512, 0, stream>>>(xb, Wt + 4 * 16384,
                                                 bq + kD, bk + kD, bv + kD, bo + kD,
                                                 mask, g1 + kD, b1 + kD, O1,
                                                 out_w, out_l1);
    tree_ln<<<256, 1024, 0, stream>>>(O1, g2 + kD, b2 + kD, out_x, nullptr, 1, 0);
}

// Round 17
// 95.008 us; speedup vs baseline: 1.4070x; 1.1108x over previous
//
#include <hip/hip_runtime.h>
#include <math.h>

typedef __bf16 bf16x8 __attribute__((ext_vector_type(8)));
typedef __bf16 bf16x4 __attribute__((ext_vector_type(4)));
typedef __bf16 bf16x2 __attribute__((ext_vector_type(2)));
typedef float f32x4 __attribute__((ext_vector_type(4)));

namespace {
constexpr int kB = 128, kS = 256, kD = 128, kH = 4;
constexpr float kEps = 1e-6f;
constexpr float kScale = 0.17677669529663687f;  // 1/sqrt(32)
constexpr float kNeg = -1000000000.0f;
constexpr float kLog2e = 1.4426950408889634f;
constexpr size_t kSZ = (size_t)kB * kS * kD;    // 4,194,304
}

// ---------------------------------------------------------------------------
// global->LDS async DMA, 16 B/lane.
// ---------------------------------------------------------------------------
__device__ __forceinline__ void glds16(const void* g, void* l) {
    __builtin_amdgcn_global_load_lds(
        (const __attribute__((address_space(1))) unsigned int*)g,
        (__attribute__((address_space(3))) unsigned int*)l, 16, 0, 0);
}

// ---------------------------------------------------------------------------
// Weight transpose + convert + FRAGMENT-MAJOR packing (round-16):
// frag(ni,ks)[lane l][j] = W^T[ni*16 + (l&15)][((l>>4) + 4*ks)*8 + j]
// ---------------------------------------------------------------------------
__global__ __launch_bounds__(256) void wtrans(
    const float* __restrict__ Wq, const float* __restrict__ Wk,
    const float* __restrict__ Wv, const float* __restrict__ Wo,
    __bf16* __restrict__ Wt)
{
    const int mtx = blockIdx.x & 3, l = blockIdx.x >> 2;
    const float* W = (mtx == 0 ? Wq : mtx == 1 ? Wk : mtx == 2 ? Wv : Wo) +
                     (size_t)l * kD * kD;
    __bf16* o = Wt + (size_t)blockIdx.x * kD * kD;
    for (int idx = threadIdx.x; idx < kD * kD; idx += 256) {
        const int k = idx >> 7, n = idx & 127;
        const int lo = n & 15, ni = n >> 4;
        const int j = k & 7, tt = k >> 3, g = tt & 3, ks = tt >> 2;
        o[((ni * 4 + ks) * 64 + g * 16 + lo) * 8 + j] = (__bf16)W[idx];
    }
}

// ---------------------------------------------------------------------------
// MEGA-KERNEL (round-16 structure) with SOFTWARE-PIPELINED produce:
// produce-compute(h+1) (pure reg MFMAs: Xs frags + W frags from global) runs
// BEFORE the post-consume barrier — after PV when s[] is dead — so waves
// de-sync across the produce window; only the LDS write stage is
// barrier-bracketed. X fragments (xa/xq) are head-invariant: hoisted.
// ---------------------------------------------------------------------------
template <int WEIGHTS, bool F32X>
__global__ __launch_bounds__(512) void mega_attn(
    const void* __restrict__ xsrc, const __bf16* __restrict__ Wp,
    const float* __restrict__ bq, const float* __restrict__ bk,
    const float* __restrict__ bv, const float* __restrict__ bo,
    const float* __restrict__ mask, const float* __restrict__ gamma,
    const float* __restrict__ beta, __bf16* __restrict__ O1,
    float* __restrict__ wout, float* __restrict__ l1out)
{
    __shared__ __bf16 Xs[256 * 128];   // 64KB swizzled x (also the residual)
    __shared__ __bf16 Kls[256 * 32];   // 16KB, XOR-swizzled chunks
    __shared__ __bf16 Vt[32][276];     // 17.25KB V^T
    __shared__ __bf16 Pl[8][16 * 64];  // 16KB per-wave quarter-P
    __shared__ __bf16 Qs[8][16 * 32];  // 8KB per-wave Q_h
    __shared__ __bf16 Ctx[128 * 128];  // 32KB swizzled ctx
    __shared__ float mb[256];

    const int t = threadIdx.x;
    const int w = t >> 6, l = t & 63, lo = l & 15, g = l >> 4;
    const int b = blockIdx.x & 127, strip = blockIdx.x >> 7;
    const int q0 = strip * 128 + w * 16;
    const int tk0 = w * 32;
    const int kswz = (lo ^ (lo >> 2)) & 3;

    const __bf16* Wqp = Wp;
    const __bf16* Wkp = Wp + 16384;
    const __bf16* Wvp = Wp + 2 * 16384;
    const __bf16* Wop = Wp + 3 * 16384;

    // ---- stage Xs (full batch, swizzled) ----
    if constexpr (F32X) {
#pragma unroll
        for (int p = 0; p < 8; ++p) {
            const int ci = p * 512 + t;
            const int row = ci >> 4, c = ci & 15;
            const float* src = (const float*)xsrc +
                               ((size_t)b * 256 + row) * 128 + c * 8;
            const float4 a0 = *(const float4*)src;
            const float4 a1 = *(const float4*)(src + 4);
            bf16x8 o;
            o[0] = (__bf16)a0.x; o[1] = (__bf16)a0.y; o[2] = (__bf16)a0.z; o[3] = (__bf16)a0.w;
            o[4] = (__bf16)a1.x; o[5] = (__bf16)a1.y; o[6] = (__bf16)a1.z; o[7] = (__bf16)a1.w;
            *(bf16x8*)&Xs[row * 128 + ((c ^ (row & 7)) << 3)] = o;
        }
    } else {
#pragma unroll
        for (int it = 0; it < 8; ++it)
            glds16((const __bf16*)xsrc + (size_t)b * 32768 + (it * 8 + w) * 512 + l * 8,
                   &Xs[(it * 8 + w) * 512]);
    }
    if (t < 256) mb[t] = mask[b * 256 + t] * (kNeg * kLog2e);
    if (WEIGHTS && blockIdx.x == 0 && t == 0) l1out[0] = 1024.0f;
    __syncthreads();

    auto wfrag = [&](const __bf16* W, int ni, int ks) {
        return *(const bf16x8*)(W + (((ni * 4 + ks) * 64 + l) << 3));
    };
    auto xfrag = [&](int row, int ks) {
        return *(const bf16x8*)&Xs[row * 128 + (((g + 4 * ks) ^ (row & 7)) << 3)];
    };

    // head-invariant X fragments (hoisted: 12 fewer ds_reads per head)
    bf16x8 xa[2][4], xq[4];
#pragma unroll
    for (int ks = 0; ks < 4; ++ks) {
        xa[0][ks] = xfrag(tk0 + lo, ks);
        xa[1][ks] = xfrag(tk0 + 16 + lo, ks);
        xq[ks] = xfrag(q0 + lo, ks);
    }

    f32x4 kacc[2][2], vacc[2][2], qacc[2];

    auto produce_compute = [&](int h) {
#pragma unroll
        for (int i = 0; i < 2; ++i)
#pragma unroll
            for (int j2 = 0; j2 < 2; ++j2) {
                kacc[i][j2] = f32x4{0.f, 0.f, 0.f, 0.f};
                vacc[i][j2] = f32x4{0.f, 0.f, 0.f, 0.f};
            }
        qacc[0] = f32x4{0.f, 0.f, 0.f, 0.f};
        qacc[1] = f32x4{0.f, 0.f, 0.f, 0.f};
#pragma unroll
        for (int ks = 0; ks < 4; ++ks) {
            const bf16x8 wk0 = wfrag(Wkp, 2 * h, ks);
            const bf16x8 wk1 = wfrag(Wkp, 2 * h + 1, ks);
            const bf16x8 wv0 = wfrag(Wvp, 2 * h, ks);
            const bf16x8 wv1 = wfrag(Wvp, 2 * h + 1, ks);
            kacc[0][0] = __builtin_amdgcn_mfma_f32_16x16x32_bf16(wk0, xa[0][ks], kacc[0][0], 0, 0, 0);
            kacc[0][1] = __builtin_amdgcn_mfma_f32_16x16x32_bf16(wk0, xa[1][ks], kacc[0][1], 0, 0, 0);
            kacc[1][0] = __builtin_amdgcn_mfma_f32_16x16x32_bf16(wk1, xa[0][ks], kacc[1][0], 0, 0, 0);
            kacc[1][1] = __builtin_amdgcn_mfma_f32_16x16x32_bf16(wk1, xa[1][ks], kacc[1][1], 0, 0, 0);
            vacc[0][0] = __builtin_amdgcn_mfma_f32_16x16x32_bf16(xa[0][ks], wv0, vacc[0][0], 0, 0, 0);
            vacc[1][0] = __builtin_amdgcn_mfma_f32_16x16x32_bf16(xa[1][ks], wv0, vacc[1][0], 0, 0, 0);
            vacc[0][1] = __builtin_amdgcn_mfma_f32_16x16x32_bf16(xa[0][ks], wv1, vacc[0][1], 0, 0, 0);
            vacc[1][1] = __builtin_amdgcn_mfma_f32_16x16x32_bf16(xa[1][ks], wv1, vacc[1][1], 0, 0, 0);
            qacc[0] = __builtin_amdgcn_mfma_f32_16x16x32_bf16(xq[ks], wfrag(Wqp, 2 * h, ks), qacc[0], 0, 0, 0);
            qacc[1] = __builtin_amdgcn_mfma_f32_16x16x32_bf16(xq[ks], wfrag(Wqp, 2 * h + 1, ks), qacc[1], 0, 0, 0);
        }
    };

    auto produce_write = [&](int h) {
#pragma unroll
        for (int dm = 0; dm < 2; ++dm) {
            const f32x4 bkv = *(const f32x4*)(bk + h * 32 + dm * 16 + 4 * g);
            const int pos = ((dm * 2 + (g >> 1)) ^ kswz) << 3;
            const int sub = (4 * g) & 7;
#pragma unroll
            for (int tj = 0; tj < 2; ++tj) {
                bf16x4 kv;
#pragma unroll
                for (int r = 0; r < 4; ++r) kv[r] = (__bf16)(kacc[dm][tj][r] + bkv[r]);
                const int key = tk0 + tj * 16 + lo;
                *(bf16x4*)&Kls[key * 32 + pos + sub] = kv;
            }
        }
#pragma unroll
        for (int nj = 0; nj < 2; ++nj) {
            const float bvv = bv[h * 32 + nj * 16 + lo];
#pragma unroll
            for (int mi = 0; mi < 2; ++mi) {
                bf16x4 vv4;
#pragma unroll
                for (int r = 0; r < 4; ++r) vv4[r] = (__bf16)(vacc[mi][nj][r] + bvv);
                *(bf16x4*)&Vt[nj * 16 + lo][tk0 + mi * 16 + 4 * g] = vv4;
            }
        }
#pragma unroll
        for (int nj = 0; nj < 2; ++nj) {
            const float bqv = bq[h * 32 + nj * 16 + lo];
#pragma unroll
            for (int r = 0; r < 4; ++r)
                Qs[w][(4 * g + r) * 32 + nj * 16 + lo] = (__bf16)(qacc[nj][r] + bqv);
        }
    };

    // prologue: head 0
    produce_compute(0);
    produce_write(0);
    __syncthreads();

#pragma unroll
    for (int h = 0; h < 4; ++h) {
        // ======== CONSUME: QK^T -> softmax -> PV ========
        const bf16x8 qf = *(const bf16x8*)&Qs[w][lo * 32 + g * 8];
        f32x4 s[16];
        __builtin_amdgcn_s_setprio(1);
#pragma unroll
        for (int f = 0; f < 16; ++f) {
            const bf16x8 kf =
                *(const bf16x8*)&Kls[(f * 16 + lo) * 32 + ((g ^ kswz) << 3)];
            s[f] = __builtin_amdgcn_mfma_f32_16x16x32_bf16(
                kf, qf, f32x4{0.f, 0.f, 0.f, 0.f}, 0, 0, 0);
        }
        __builtin_amdgcn_s_setprio(0);

        float ls = 0.f;
#pragma unroll
        for (int f = 0; f < 16; ++f) {
            const f32x4 mk = *(const f32x4*)&mb[f * 16 + g * 4];
#pragma unroll
            for (int r = 0; r < 4; ++r) {
                const float p = __builtin_amdgcn_exp2f(
                    s[f][r] * (kScale * kLog2e) + mk[r]);
                s[f][r] = p;
                ls += p;
            }
        }
        ls += __shfl_xor(ls, 16, 64);
        ls += __shfl_xor(ls, 32, 64);

        if constexpr (WEIGHTS) {
            if (strip == 1 && w == 7 && lo == 15) {
                const float inv = 1.f / ls;
                float* wrow = wout + ((size_t)b * 4 + h) * 256;
#pragma unroll
                for (int f = 0; f < 16; ++f)
#pragma unroll
                    for (int r = 0; r < 4; ++r)
                        wrow[f * 16 + g * 4 + r] = s[f][r] * inv;
            }
        }

        // PV in four quarter-P passes (64 keys each); s dead afterwards
        f32x4 o[2] = {f32x4{0.f, 0.f, 0.f, 0.f}, f32x4{0.f, 0.f, 0.f, 0.f}};
#pragma unroll
        for (int qt = 0; qt < 4; ++qt) {
#pragma unroll
            for (int fl = 0; fl < 4; ++fl) {
                const int ff = qt * 4 + fl;
#pragma unroll
                for (int pr = 0; pr < 2; ++pr) {
                    bf16x2 pk;
                    pk[0] = (__bf16)s[ff][2 * pr];
                    pk[1] = (__bf16)s[ff][2 * pr + 1];
                    const int e = fl * 16 + 4 * g + 2 * pr;
                    const int addr =
                        lo * 64 + ((((e >> 3) ^ (lo & 7)) << 3) | (e & 7));
                    *(bf16x2*)&Pl[w][addr] = pk;
                }
            }
            __builtin_amdgcn_s_setprio(1);
#pragma unroll
            for (int ksl = 0; ksl < 2; ++ksl) {
                const int cc = ksl * 4 + g;
                const bf16x8 pa =
                    *(const bf16x8*)&Pl[w][lo * 64 + ((cc ^ (lo & 7)) << 3)];
#pragma unroll
                for (int nf = 0; nf < 2; ++nf) {
                    const bf16x8 bvv =
                        *(const bf16x8*)&Vt[nf * 16 + lo][(qt * 2 + ksl) * 32 + g * 8];
                    o[nf] = __builtin_amdgcn_mfma_f32_16x16x32_bf16(pa, bvv, o[nf], 0, 0, 0);
                }
            }
            __builtin_amdgcn_s_setprio(0);
        }

        // ---- pipelined produce-compute for next head (pre-barrier) ----
        if (h < 3) produce_compute(h + 1);

        // normalized ctx -> swizzled LDS tile (cols h*32..h*32+31)
#pragma unroll
        for (int r = 0; r < 4; ++r) {
            const float inv = 1.f / __shfl(ls, 4 * g + r, 64);
            const int crow = w * 16 + g * 4 + r;
#pragma unroll
            for (int nf = 0; nf < 2; ++nf) {
                const int col = h * 32 + nf * 16 + lo;
                const int chunk = (col >> 3) ^ (crow & 7);
                Ctx[crow * 128 + (chunk << 3) + (col & 7)] = (__bf16)(o[nf][r] * inv);
            }
        }
        if (h < 3) {
            __syncthreads();          // all Kls/Vt reads of head h complete
            produce_write(h + 1);     // only the write stage is serialized
            __syncthreads();
        }
    }

    // ======== O-projection + residual + LN1 ========
    const size_t m0 = (size_t)b * 256 + strip * 128;
    f32x4 acc[8];
#pragma unroll
    for (int ni = 0; ni < 8; ++ni) acc[ni] = f32x4{0.f, 0.f, 0.f, 0.f};

    const int arow = w * 16 + lo;
#pragma unroll
    for (int ks = 0; ks < 4; ++ks) {
        const bf16x8 av =
            *(const bf16x8*)&Ctx[arow * 128 + (((g + 4 * ks) ^ (arow & 7)) << 3)];
#pragma unroll
        for (int ni = 0; ni < 8; ++ni)
            acc[ni] = __builtin_amdgcn_mfma_f32_16x16x32_bf16(
                av, wfrag(Wop, ni, ks), acc[ni], 0, 0, 0);
    }

    float bcol[8], ga[8], be[8];
#pragma unroll
    for (int ni = 0; ni < 8; ++ni) {
        bcol[ni] = bo[ni * 16 + lo];
        ga[ni] = gamma[ni * 16 + lo];
        be[ni] = beta[ni * 16 + lo];
    }

    float vv[4][8];
    float s[4] = {0, 0, 0, 0}, s2[4] = {0, 0, 0, 0};
#pragma unroll
    for (int r = 0; r < 4; ++r) {
        const int local = strip * 128 + w * 16 + g * 4 + r;
#pragma unroll
        for (int ni = 0; ni < 8; ++ni) {
            const int col = ni * 16 + lo;
            const int chunk = (col >> 3) ^ (local & 7);
            const float rv = (float)Xs[local * 128 + (chunk << 3) + (col & 7)];
            const float x = acc[ni][r] + bcol[ni] + rv;
            vv[r][ni] = x; s[r] += x; s2[r] += x * x;
        }
    }
#pragma unroll
    for (int r = 0; r < 4; ++r)
#pragma unroll
        for (int o = 1; o < 16; o <<= 1) {
            s[r] += __shfl_xor(s[r], o, 64);
            s2[r] += __shfl_xor(s2[r], o, 64);
        }
#pragma unroll
    for (int r = 0; r < 4; ++r) {
        const float mu = s[r] * (1.f / 128.f);
        const float var = s2[r] * (1.f / 128.f) - mu * mu;
        const float rs = rsqrtf(var + kEps);
        const size_t mm = m0 + w * 16 + g * 4 + r;
#pragma unroll
        for (int ni = 0; ni < 8; ++ni)
            O1[mm * 128 + ni * 16 + lo] =
                (__bf16)(ga[ni] * (vv[r][ni] - mu) * rs + be[ni]);
    }
}

// ---------------------------------------------------------------------------
// FUSED tree aggregation + residual + LayerNorm2 (round-15/16 known-good).
// ---------------------------------------------------------------------------
__global__ __launch_bounds__(1024) void tree_ln(
    const __bf16* __restrict__ o1, const float* __restrict__ gamma,
    const float* __restrict__ beta, float* __restrict__ xo,
    __bf16* __restrict__ xb, int wf32, int wbf16)
{
    __shared__ float e[127 * 132];   // internal nodes only
    const int isleaf = blockIdx.x >> 7;
    const int b = blockIdx.x & 127;
    const int t = threadIdx.x;
    const __bf16* ob = o1 + (size_t)b * 256 * 128;
    const int wv = t >> 6, lane = t & 63;
    const float2 gv = *(const float2*)(gamma + lane * 2);
    const float2 bb = *(const float2*)(beta + lane * 2);
    const int c = lane * 2;

    auto ln_store = [&](int row, float y0, float y1) {
        float s = y0 + y1, s2 = y0 * y0 + y1 * y1;
#pragma unroll
        for (int o = 1; o < 64; o <<= 1) {
            s += __shfl_xor(s, o, 64);
            s2 += __shfl_xor(s2, o, 64);
        }
        const float mu = s * (1.f / 128.f);
        const float var = s2 * (1.f / 128.f) - mu * mu;
        const float rs = rsqrtf(var + kEps);
        const float r0 = gv.x * (y0 - mu) * rs + bb.x;
        const float r1 = gv.y * (y1 - mu) * rs + bb.y;
        const size_t rowoff = ((size_t)b * 256 + row) * 128;
        if (wf32) {
            float2 o2; o2.x = r0; o2.y = r1;
            *(float2*)(xo + rowoff + c) = o2;
        }
        if (wbf16) {
            const int chunk = (c >> 3) ^ (row & 7);
            bf16x2 ob2; ob2[0] = (__bf16)r0; ob2[1] = (__bf16)r1;
            *(bf16x2*)(xb + rowoff + chunk * 8 + (c & 7)) = ob2;
        }
    };

    if (isleaf) {
        for (int row = 128 + wv; row < 256; row += 16) {
            const bf16x2 v = *(const bf16x2*)(ob + (size_t)row * 128 + c);
            ln_store(row, 2.f * (float)v[0], 2.f * (float)v[1]);
        }
        return;
    }

    // level 6 straight from global: parents 63..126, children 127..254
    {
        const int p = 63 + (t >> 4);
        const int cg = (t & 15) * 8;
        const bf16x8 c1 = *(const bf16x8*)(ob + (size_t)(2 * p + 1) * 128 + cg);
        const bf16x8 c2 = *(const bf16x8*)(ob + (size_t)(2 * p + 2) * 128 + cg);
        f32x4 r0, r1;
#pragma unroll
        for (int i = 0; i < 4; ++i)
            r0[i] = tanhf((float)c1[i] + (float)c2[i]);
#pragma unroll
        for (int i = 0; i < 4; ++i)
            r1[i] = tanhf((float)c1[4 + i] + (float)c2[4 + i]);
        *(f32x4*)&e[p * 132 + cg] = r0;
        *(f32x4*)&e[p * 132 + cg + 4] = r1;
    }
    __syncthreads();

    {
        const int col = wv * 8 + (lane & 7);
        const int nsub = lane >> 3;
        for (int lvl = 5; lvl >= 0; --lvl) {
            const int p0 = (1 << lvl) - 1;
            const int cnt = 1 << lvl;
            for (int base = 0; base < cnt; base += 8) {
                const int p = p0 + base + nsub;
                if (base + nsub < cnt) {
                    e[p * 132 + col] =
                        tanhf(e[(2 * p + 1) * 132 + col] + e[(2 * p + 2) * 132 + col]);
                }
            }
        }
    }
    __syncthreads();

    for (int row = wv; row < 128; row += 16) {
        const bf16x2 v = *(const bf16x2*)(ob + (size_t)row * 128 + c);
        float y0, y1;
        if (row < 127) {
            y0 = (float)v[0] + e[row * 132 + c];
            y1 = (float)v[1] + e[row * 132 + c + 1];
        } else {
            y0 = 2.f * (float)v[0];
            y1 = 2.f * (float)v[1];
        }
        ln_store(row, y0, y1);
    }
}

// ---------------------------------------------------------------------------
extern "C" void kernel_launch(void* const* d_in, const int* in_sizes, int n_in,
                              void* d_out, int out_size, void* d_ws, size_t ws_size,
                              hipStream_t stream)
{
    (void)in_sizes; (void)n_in; (void)out_size; (void)ws_size;

    const float* x_in = (const float*)d_in[0];
    const float* mask = (const float*)d_in[1];
    const float* Wq = (const float*)d_in[5];
    const float* bq = (const float*)d_in[6];
    const float* Wk = (const float*)d_in[7];
    const float* bk = (const float*)d_in[8];
    const float* Wv = (const float*)d_in[9];
    const float* bv = (const float*)d_in[10];
    const float* Wo = (const float*)d_in[11];
    const float* bo = (const float*)d_in[12];
    const float* g1 = (const float*)d_in[13];
    const float* b1 = (const float*)d_in[14];
    const float* g2 = (const float*)d_in[15];
    const float* b2 = (const float*)d_in[16];

    float* out_x = (float*)d_out;
    float* out_l1 = out_x + kSZ;
    float* out_w = out_l1 + 1;

    char* wsb = (char*)d_ws;
    __bf16* O1 = (__bf16*)wsb;                   // 8MB
    __bf16* xb = (__bf16*)(wsb + kSZ * 2);       // 8MB, pre-swizzled bf16 x
    __bf16* Wt = (__bf16*)(wsb + 2 * kSZ * 2);   // 8 * 16384 bf16, frag-major

    wtrans<<<8, 256, 0, stream>>>(Wq, Wk, Wv, Wo, Wt);

    // ---- layer 0 (f32 x_in) ----
    mega_attn<0, true><<<256, 512, 0, stream>>>(x_in, Wt, bq, bk, bv, bo,
                                                mask, g1, b1, O1,
                                                nullptr, nullptr);
    tree_ln<<<256, 1024, 0, stream>>>(O1, g2, b2, nullptr, xb, 0, 1);

    // ---- layer 1 (bf16 xb, pre-swizzled) ----
    mega_attn<1, false><<<256, 512, 0, stream>>>(xb, Wt + 4 * 16384,
                                                 bq + kD, bk + kD, bv + kD, bo + kD,
                                                 mask, g1 + kD, b1 + kD, O1,
                                                 out_w, out_l1);
    tree_ln<<<256, 1024, 0, stream>>>(O1, g2 + kD, b2 + kD, out_x, nullptr, 1, 0);
}